// Round 2
// baseline (1084.350 us; speedup 1.0000x reference)
//
#include <hip/hip_runtime.h>
#include <math.h>

// FLASH (GAU-style) fused block — fp32 compute, bf16 intermediates.
// b=4, n=4096, dim=512, hid=1024, qk=128, group=256.
// WS footprint: 144 MB (qk 8 + h 64 + attn 8 + kv 32 + gated 32).
// normed (fp32 32 MB) lives in d_out until final_kernel overwrites it.

#define BATCH 4
#define SEQ   4096
#define TROWS 16384      // BATCH*SEQ
#define DIMD  512
#define HIDD  1024
#define QKD   128
#define GRP   256
#define NGRP  16         // SEQ/GRP
#define BGRP  64         // BATCH*NGRP

#define TS 64
#define KT 16

typedef unsigned short bfraw;

__device__ __forceinline__ float bf2f(bfraw u) {
    union { float f; unsigned int i; } c;
    c.i = ((unsigned int)u) << 16;
    return c.f;
}
__device__ __forceinline__ bfraw f2bf(float f) {
    unsigned int x = __float_as_uint(f);
    unsigned int r = (x + 0x7fffu + ((x >> 16) & 1u)) >> 16;   // RNE
    return (bfraw)r;
}
__device__ __forceinline__ float silu_f(float z) {
    return z / (1.f + __expf(-z));
}

// ---------------- LayerNorm: one wave per row of 512 ----------------
__global__ __launch_bounds__(256) void ln_kernel(const float* __restrict__ x,
                                                 const float* __restrict__ w,
                                                 const float* __restrict__ b,
                                                 float* __restrict__ out) {
    int row  = blockIdx.x * 4 + (threadIdx.x >> 6);
    int lane = threadIdx.x & 63;
    const float* xr = x + (size_t)row * DIMD;
    float4 v0 = ((const float4*)xr)[lane];
    float4 v1 = ((const float4*)xr)[lane + 64];
    float s  = v0.x + v0.y + v0.z + v0.w + v1.x + v1.y + v1.z + v1.w;
    float ss = v0.x*v0.x + v0.y*v0.y + v0.z*v0.z + v0.w*v0.w
             + v1.x*v1.x + v1.y*v1.y + v1.z*v1.z + v1.w*v1.w;
    #pragma unroll
    for (int off = 32; off; off >>= 1) {
        s  += __shfl_xor(s, off);
        ss += __shfl_xor(ss, off);
    }
    float mu  = s * (1.f / DIMD);
    float var = ss * (1.f / DIMD) - mu * mu;
    float inv = rsqrtf(var + 1e-5f);
    float4 w0 = ((const float4*)w)[lane],  w1 = ((const float4*)w)[lane + 64];
    float4 b0 = ((const float4*)b)[lane],  b1 = ((const float4*)b)[lane + 64];
    float4 o0, o1;
    o0.x = (v0.x - mu) * inv * w0.x + b0.x;
    o0.y = (v0.y - mu) * inv * w0.y + b0.y;
    o0.z = (v0.z - mu) * inv * w0.z + b0.z;
    o0.w = (v0.w - mu) * inv * w0.w + b0.w;
    o1.x = (v1.x - mu) * inv * w1.x + b1.x;
    o1.y = (v1.y - mu) * inv * w1.y + b1.y;
    o1.z = (v1.z - mu) * inv * w1.z + b1.z;
    o1.w = (v1.w - mu) * inv * w1.w + b1.w;
    float* orow = out + (size_t)row * DIMD;
    ((float4*)orow)[lane]      = o0;
    ((float4*)orow)[lane + 64] = o1;
}

// ------------- inner-product tile helper (64x64 tile, 16x16 threads, 4x4/thread) -------------
__device__ __forceinline__ void mma_tile(const float As[KT][TS + 4],
                                         const float Bs[KT][TS + 4],
                                         float acc[4][4], int ty, int tx) {
    #pragma unroll
    for (int kk = 0; kk < KT; ++kk) {
        float a[4], bb[4];
        #pragma unroll
        for (int i = 0; i < 4; ++i) a[i] = As[kk][ty * 4 + i];
        #pragma unroll
        for (int j = 0; j < 4; ++j) bb[j] = Bs[kk][tx * 4 + j];
        #pragma unroll
        for (int i = 0; i < 4; ++i)
            #pragma unroll
            for (int j = 0; j < 4; ++j) acc[i][j] = fmaf(a[i], bb[j], acc[i][j]);
    }
}

// ------------- GEMM + bias + SiLU: C[M,N] = silu(A[M,K] @ W[K,N] + bias) -------------
template <bool BF16OUT>
__global__ __launch_bounds__(256) void gemm_bias_silu(const float* __restrict__ A,
                                                      const float* __restrict__ W,
                                                      const float* __restrict__ bias,
                                                      void* __restrict__ Cv,
                                                      int M, int N, int K) {
    __shared__ float As[KT][TS + 4];
    __shared__ float Bs[KT][TS + 4];
    int t = threadIdx.x;
    int tx = t & 15, ty = t >> 4;
    int row0 = blockIdx.y * TS, col0 = blockIdx.x * TS;
    float acc[4][4] = {};
    for (int k0 = 0; k0 < K; k0 += KT) {
        int r  = t >> 2;
        int c4 = (t & 3) << 2;
        float4 av = *(const float4*)&A[(size_t)(row0 + r) * K + k0 + c4];
        As[c4 + 0][r] = av.x; As[c4 + 1][r] = av.y;
        As[c4 + 2][r] = av.z; As[c4 + 3][r] = av.w;
        int br = t >> 4;
        int bc = (t & 15) << 2;
        float4 wv = *(const float4*)&W[(size_t)(k0 + br) * N + col0 + bc];
        *(float4*)&Bs[br][bc] = wv;
        __syncthreads();
        mma_tile(As, Bs, acc, ty, tx);
        __syncthreads();
    }
    #pragma unroll
    for (int i = 0; i < 4; ++i) {
        int row = row0 + ty * 4 + i;
        int col = col0 + tx * 4;
        float z0 = silu_f(acc[i][0] + bias[col + 0]);
        float z1 = silu_f(acc[i][1] + bias[col + 1]);
        float z2 = silu_f(acc[i][2] + bias[col + 2]);
        float z3 = silu_f(acc[i][3] + bias[col + 3]);
        if (BF16OUT) {
            ushort4 s;
            s.x = f2bf(z0); s.y = f2bf(z1); s.z = f2bf(z2); s.w = f2bf(z3);
            *(ushort4*)&((bfraw*)Cv)[(size_t)row * N + col] = s;
        } else {
            float4 r = make_float4(z0, z1, z2, z3);
            *(float4*)&((float*)Cv)[(size_t)row * N + col] = r;
        }
    }
}

// ------------- sim: attn[bg][i][j] = mask * relu(qq_i . qk_j / G)^2  (bf16 out) -------------
__global__ __launch_bounds__(256) void sim_kernel(const float* __restrict__ qk,
                                                  const float* __restrict__ gamma,
                                                  const float* __restrict__ beta,
                                                  bfraw* __restrict__ attn) {
    int bg   = blockIdx.z;
    int row0 = blockIdx.y * TS;
    int col0 = blockIdx.x * TS;
    if (col0 > row0) return;   // strictly-above-diagonal tiles are never read
    int t = threadIdx.x;
    int tx = t & 15, ty = t >> 4;
    bfraw* ag = attn + (size_t)bg * GRP * GRP;
    __shared__ float As[KT][TS + 4];
    __shared__ float Bs[KT][TS + 4];
    float acc[4][4] = {};
    for (int k0 = 0; k0 < QKD; k0 += KT) {
        int r  = t >> 2;
        int c4 = (t & 3) << 2;
        float4 g0 = *(const float4*)&gamma[0 * QKD + k0 + c4];
        float4 e0 = *(const float4*)&beta [0 * QKD + k0 + c4];
        float4 qv = *(const float4*)&qk[(size_t)(bg * GRP + row0 + r) * QKD + k0 + c4];
        As[c4 + 0][r] = qv.x * g0.x + e0.x;
        As[c4 + 1][r] = qv.y * g0.y + e0.y;
        As[c4 + 2][r] = qv.z * g0.z + e0.z;
        As[c4 + 3][r] = qv.w * g0.w + e0.w;
        float4 g2 = *(const float4*)&gamma[2 * QKD + k0 + c4];
        float4 e2 = *(const float4*)&beta [2 * QKD + k0 + c4];
        float4 kv = *(const float4*)&qk[(size_t)(bg * GRP + col0 + r) * QKD + k0 + c4];
        Bs[c4 + 0][r] = kv.x * g2.x + e2.x;
        Bs[c4 + 1][r] = kv.y * g2.y + e2.y;
        Bs[c4 + 2][r] = kv.z * g2.z + e2.z;
        Bs[c4 + 3][r] = kv.w * g2.w + e2.w;
        __syncthreads();
        mma_tile(As, Bs, acc, ty, tx);
        __syncthreads();
    }
    #pragma unroll
    for (int i = 0; i < 4; ++i) {
        int ig = row0 + ty * 4 + i;
        ushort4 r;
        bfraw* pr = &r.x;
        #pragma unroll
        for (int j = 0; j < 4; ++j) {
            int jg = col0 + tx * 4 + j;
            float s = acc[i][j] * (1.f / GRP);
            s = fmaxf(s, 0.f);
            s = s * s;
            pr[j] = (jg > ig) ? (bfraw)0 : f2bf(s);
        }
        *(ushort4*)&ag[(size_t)ig * GRP + col0 + tx * 4] = r;
    }
}

// ------------- kv[bg][d][e] = (1/G) * sum_n lk[n][d] * vv[n][e]  (fp32 out) -------------
__global__ __launch_bounds__(256) void kv_kernel(const float* __restrict__ qk,
                                                 const float* __restrict__ gamma,
                                                 const float* __restrict__ beta,
                                                 const bfraw* __restrict__ h,
                                                 float* __restrict__ kv) {
    int bg   = blockIdx.z;
    int d0   = blockIdx.y * TS;   // 0 or 64
    int col0 = blockIdx.x * TS;
    int t = threadIdx.x;
    int tx = t & 15, ty = t >> 4;
    __shared__ float As[KT][TS + 4];
    __shared__ float Bs[KT][TS + 4];
    float acc[4][4] = {};
    for (int n0 = 0; n0 < GRP; n0 += KT) {
        int c  = t >> 4;            // n offset 0..15
        int d4 = (t & 15) << 2;     // d offset 0..60
        float4 qv = *(const float4*)&qk[(size_t)(bg * GRP + n0 + c) * QKD + d0 + d4];
        float4 g3 = *(const float4*)&gamma[3 * QKD + d0 + d4];
        float4 e3 = *(const float4*)&beta [3 * QKD + d0 + d4];
        float4 avv = make_float4(qv.x * g3.x + e3.x, qv.y * g3.y + e3.y,
                                 qv.z * g3.z + e3.z, qv.w * g3.w + e3.w);
        *(float4*)&As[c][d4] = avv;
        int br = t >> 4;
        int bc = (t & 15) << 2;
        ushort4 wv = *(const ushort4*)&h[(size_t)(bg * GRP + n0 + br) * (2 * HIDD) + col0 + bc];
        Bs[br][bc + 0] = bf2f(wv.x); Bs[br][bc + 1] = bf2f(wv.y);
        Bs[br][bc + 2] = bf2f(wv.z); Bs[br][bc + 3] = bf2f(wv.w);
        __syncthreads();
        mma_tile(As, Bs, acc, ty, tx);
        __syncthreads();
    }
    #pragma unroll
    for (int i = 0; i < 4; ++i) {
        int d = d0 + ty * 4 + i;
        float4 r = make_float4(acc[i][0] * (1.f / GRP), acc[i][1] * (1.f / GRP),
                               acc[i][2] * (1.f / GRP), acc[i][3] * (1.f / GRP));
        *(float4*)&kv[(size_t)bg * QKD * HIDD + (size_t)d * HIDD + col0 + tx * 4] = r;
    }
}

// ------------- exclusive cumsum of kv over group dim (per batch) -------------
__global__ __launch_bounds__(256) void cumsum_kernel(float* __restrict__ kv) {
    int idx  = blockIdx.x * 256 + threadIdx.x;        // 0 .. 4*128*1024-1
    int bidx = idx >> 17;                             // / (128*1024)
    int off  = idx & 131071;
    float* p = kv + (size_t)bidx * (NGRP * QKD * HIDD) + off;
    float run = 0.f;
    #pragma unroll
    for (int g = 0; g < NGRP; ++g) {
        float tv = p[(size_t)g * QKD * HIDD];
        p[(size_t)g * QKD * HIDD] = run;
        run += tv;
    }
}

// ------------- gated[bg] = gate .* (attn@vv + lq@kv_ex)  (bf16 out) -------------
__global__ __launch_bounds__(256) void quadlin_kernel(const float* __restrict__ qk,
                                                      const float* __restrict__ gamma,
                                                      const float* __restrict__ beta,
                                                      const bfraw* __restrict__ attn,
                                                      const bfraw* __restrict__ h,
                                                      const float* __restrict__ kv,
                                                      bfraw* __restrict__ gated) {
    int bg   = blockIdx.z;
    int row0 = blockIdx.y * TS;
    int col0 = blockIdx.x * TS;
    int t = threadIdx.x;
    int tx = t & 15, ty = t >> 4;
    const bfraw* ag = attn + (size_t)bg * GRP * GRP;
    __shared__ float As[KT][TS + 4];
    __shared__ float Bs[KT][TS + 4];
    float acc[4][4] = {};
    // Part 1: quadratic attention, causal -> k < row0+64
    int kmax = row0 + TS;
    for (int k0 = 0; k0 < kmax; k0 += KT) {
        int r  = t >> 2;
        int c4 = (t & 3) << 2;
        ushort4 av = *(const ushort4*)&ag[(size_t)(row0 + r) * GRP + k0 + c4];
        As[c4 + 0][r] = bf2f(av.x); As[c4 + 1][r] = bf2f(av.y);
        As[c4 + 2][r] = bf2f(av.z); As[c4 + 3][r] = bf2f(av.w);
        int br = t >> 4;
        int bc = (t & 15) << 2;
        ushort4 wv = *(const ushort4*)&h[(size_t)(bg * GRP + k0 + br) * (2 * HIDD) + col0 + bc];
        Bs[br][bc + 0] = bf2f(wv.x); Bs[br][bc + 1] = bf2f(wv.y);
        Bs[br][bc + 2] = bf2f(wv.z); Bs[br][bc + 3] = bf2f(wv.w);
        __syncthreads();
        mma_tile(As, Bs, acc, ty, tx);
        __syncthreads();
    }
    // Part 2: linear attention, lq @ kv_ex
    const float* kvg = kv + (size_t)bg * QKD * HIDD;
    for (int d0 = 0; d0 < QKD; d0 += KT) {
        int r  = t >> 2;
        int c4 = (t & 3) << 2;
        float4 g1 = *(const float4*)&gamma[1 * QKD + d0 + c4];
        float4 e1 = *(const float4*)&beta [1 * QKD + d0 + c4];
        float4 qv = *(const float4*)&qk[(size_t)(bg * GRP + row0 + r) * QKD + d0 + c4];
        As[c4 + 0][r] = qv.x * g1.x + e1.x;
        As[c4 + 1][r] = qv.y * g1.y + e1.y;
        As[c4 + 2][r] = qv.z * g1.z + e1.z;
        As[c4 + 3][r] = qv.w * g1.w + e1.w;
        int br = t >> 4;
        int bc = (t & 15) << 2;
        float4 wv = *(const float4*)&kvg[(size_t)(d0 + br) * HIDD + col0 + bc];
        *(float4*)&Bs[br][bc] = wv;
        __syncthreads();
        mma_tile(As, Bs, acc, ty, tx);
        __syncthreads();
    }
    // Epilogue: multiply by gate, store bf16
    #pragma unroll
    for (int i = 0; i < 4; ++i) {
        int row = bg * GRP + row0 + ty * 4 + i;
        int col = col0 + tx * 4;
        ushort4 gv = *(const ushort4*)&h[(size_t)row * (2 * HIDD) + HIDD + col];
        ushort4 s;
        s.x = f2bf(acc[i][0] * bf2f(gv.x));
        s.y = f2bf(acc[i][1] * bf2f(gv.y));
        s.z = f2bf(acc[i][2] * bf2f(gv.z));
        s.w = f2bf(acc[i][3] * bf2f(gv.w));
        *(ushort4*)&gated[(size_t)row * HIDD + col] = s;
    }
}

// ------------- final: out = gated @ Wo + bo + x -------------
__global__ __launch_bounds__(256) void final_kernel(const bfraw* __restrict__ gated,
                                                    const float* __restrict__ Wo,
                                                    const float* __restrict__ bo,
                                                    const float* __restrict__ x,
                                                    float* __restrict__ out) {
    int row0 = blockIdx.y * TS;
    int col0 = blockIdx.x * TS;
    int t = threadIdx.x;
    int tx = t & 15, ty = t >> 4;
    __shared__ float As[KT][TS + 4];
    __shared__ float Bs[KT][TS + 4];
    float acc[4][4] = {};
    for (int k0 = 0; k0 < HIDD; k0 += KT) {
        int r  = t >> 2;
        int c4 = (t & 3) << 2;
        ushort4 av = *(const ushort4*)&gated[(size_t)(row0 + r) * HIDD + k0 + c4];
        As[c4 + 0][r] = bf2f(av.x); As[c4 + 1][r] = bf2f(av.y);
        As[c4 + 2][r] = bf2f(av.z); As[c4 + 3][r] = bf2f(av.w);
        int br = t >> 4;
        int bc = (t & 15) << 2;
        float4 wv = *(const float4*)&Wo[(size_t)(k0 + br) * DIMD + col0 + bc];
        *(float4*)&Bs[br][bc] = wv;
        __syncthreads();
        mma_tile(As, Bs, acc, ty, tx);
        __syncthreads();
    }
    #pragma unroll
    for (int i = 0; i < 4; ++i) {
        int row = row0 + ty * 4 + i;
        int col = col0 + tx * 4;
        float4 xv = *(const float4*)&x[(size_t)row * DIMD + col];
        float4 r;
        r.x = acc[i][0] + bo[col + 0] + xv.x;
        r.y = acc[i][1] + bo[col + 1] + xv.y;
        r.z = acc[i][2] + bo[col + 2] + xv.z;
        r.w = acc[i][3] + bo[col + 3] + xv.w;
        *(float4*)&out[(size_t)row * DIMD + col] = r;
    }
}

extern "C" void kernel_launch(void* const* d_in, const int* in_sizes, int n_in,
                              void* d_out, int out_size, void* d_ws, size_t ws_size,
                              hipStream_t stream) {
    const float* x     = (const float*)d_in[0];
    const float* ln_w  = (const float*)d_in[1];
    const float* ln_b  = (const float*)d_in[2];
    const float* Wh    = (const float*)d_in[3];
    const float* bh    = (const float*)d_in[4];
    const float* Wqk   = (const float*)d_in[5];
    const float* bqk   = (const float*)d_in[6];
    const float* gamma = (const float*)d_in[7];
    const float* beta  = (const float*)d_in[8];
    const float* Wo    = (const float*)d_in[9];
    const float* bo    = (const float*)d_in[10];
    float* out = (float*)d_out;

    // normed (fp32, 32 MB) lives in d_out until final_kernel overwrites it.
    float* normed = (float*)d_out;

    // ws layout (byte offsets), total 144 MB:
    char* wsb = (char*)d_ws;
    float* qk    = (float*)(wsb);                    //  8 MB fp32 [16384 x 128]
    bfraw* h     = (bfraw*)(wsb + 8388608);          // 64 MB bf16 [16384 x 2048]
    bfraw* attn  = (bfraw*)(wsb + 75497472);         //  8 MB bf16 [64 x 256 x 256]
    float* kv    = (float*)(wsb + 83886080);         // 32 MB fp32 [64 x 128 x 1024]
    bfraw* gated = (bfraw*)(wsb + 117440512);        // 32 MB bf16 [16384 x 1024]
    // end: 150,994,944 bytes

    // 1. LayerNorm -> normed (in d_out)
    ln_kernel<<<TROWS / 4, 256, 0, stream>>>(x, ln_w, ln_b, normed);
    // 2. h = silu(normed @ Wh + bh)   [16384 x 2048] bf16
    gemm_bias_silu<true><<<dim3(2 * HIDD / TS, TROWS / TS), 256, 0, stream>>>(
        normed, Wh, bh, (void*)h, TROWS, 2 * HIDD, DIMD);
    // 3. qk = silu(normed @ Wqk + bqk)  [16384 x 128] fp32
    gemm_bias_silu<false><<<dim3(QKD / TS, TROWS / TS), 256, 0, stream>>>(
        normed, Wqk, bqk, (void*)qk, TROWS, QKD, DIMD);
    // 4. attn = mask(relu(qq @ kk^T / G)^2)  per group (lower-tri tiles only)
    sim_kernel<<<dim3(GRP / TS, GRP / TS, BGRP), 256, 0, stream>>>(qk, gamma, beta, attn);
    // 5. kv = lk^T @ vv / G
    kv_kernel<<<dim3(HIDD / TS, QKD / TS, BGRP), 256, 0, stream>>>(qk, gamma, beta, h, kv);
    // 6. exclusive cumsum over groups
    cumsum_kernel<<<(BATCH * QKD * HIDD) / 256, 256, 0, stream>>>(kv);
    // 7. gated = gate .* (attn@vv + lq@kv_ex)
    quadlin_kernel<<<dim3(HIDD / TS, GRP / TS, BGRP), 256, 0, stream>>>(
        qk, gamma, beta, attn, h, kv, gated);
    // 8. out = gated @ Wo + bo + x
    final_kernel<<<dim3(DIMD / TS, TROWS / TS), 256, 0, stream>>>(gated, Wo, bo, x, out);
}

// Round 3
// 509.189 us; speedup vs baseline: 2.1296x; 2.1296x over previous
//
#include <hip/hip_runtime.h>
#include <math.h>

// FLASH (GAU-style) fused block. Round 2: big GEMMs on bf16 MFMA.
// b=4, n=4096, dim=512, hid=1024, qk=128, group=256.

#define BATCH 4
#define SEQ   4096
#define TROWS 16384      // BATCH*SEQ
#define DIMD  512
#define HIDD  1024
#define QKD   128
#define GRP   256
#define NGRP  16         // SEQ/GRP
#define BGRP  64         // BATCH*NGRP

#define TS 64
#define KT 16

typedef unsigned short bfraw;
typedef __attribute__((ext_vector_type(8))) short bf16x8;
typedef __attribute__((ext_vector_type(4))) float f32x4;

__device__ __forceinline__ float bf2f(bfraw u) {
    union { float f; unsigned int i; } c;
    c.i = ((unsigned int)u) << 16;
    return c.f;
}
__device__ __forceinline__ bfraw f2bf(float f) {
    unsigned int x = __float_as_uint(f);
    unsigned int r = (x + 0x7fffu + ((x >> 16) & 1u)) >> 16;   // RNE
    return (bfraw)r;
}
__device__ __forceinline__ float silu_f(float z) {
    return z / (1.f + __expf(-z));
}
__device__ __forceinline__ void gload_lds16(const void* g, void* l) {
    __builtin_amdgcn_global_load_lds(
        (const __attribute__((address_space(1))) unsigned int*)g,
        (__attribute__((address_space(3))) unsigned int*)l, 16, 0, 0);
}

// ---------------- LayerNorm: one wave per row of 512; fp32 + bf16 outputs ----------------
__global__ __launch_bounds__(256) void ln_kernel(const float* __restrict__ x,
                                                 const float* __restrict__ w,
                                                 const float* __restrict__ b,
                                                 float* __restrict__ outf,
                                                 bfraw* __restrict__ outb) {
    int row  = blockIdx.x * 4 + (threadIdx.x >> 6);
    int lane = threadIdx.x & 63;
    const float* xr = x + (size_t)row * DIMD;
    float4 v0 = ((const float4*)xr)[lane];
    float4 v1 = ((const float4*)xr)[lane + 64];
    float s  = v0.x + v0.y + v0.z + v0.w + v1.x + v1.y + v1.z + v1.w;
    float ss = v0.x*v0.x + v0.y*v0.y + v0.z*v0.z + v0.w*v0.w
             + v1.x*v1.x + v1.y*v1.y + v1.z*v1.z + v1.w*v1.w;
    #pragma unroll
    for (int off = 32; off; off >>= 1) {
        s  += __shfl_xor(s, off);
        ss += __shfl_xor(ss, off);
    }
    float mu  = s * (1.f / DIMD);
    float var = ss * (1.f / DIMD) - mu * mu;
    float inv = rsqrtf(var + 1e-5f);
    float4 w0 = ((const float4*)w)[lane],  w1 = ((const float4*)w)[lane + 64];
    float4 b0 = ((const float4*)b)[lane],  b1 = ((const float4*)b)[lane + 64];
    float4 o0, o1;
    o0.x = (v0.x - mu) * inv * w0.x + b0.x;
    o0.y = (v0.y - mu) * inv * w0.y + b0.y;
    o0.z = (v0.z - mu) * inv * w0.z + b0.z;
    o0.w = (v0.w - mu) * inv * w0.w + b0.w;
    o1.x = (v1.x - mu) * inv * w1.x + b1.x;
    o1.y = (v1.y - mu) * inv * w1.y + b1.y;
    o1.z = (v1.z - mu) * inv * w1.z + b1.z;
    o1.w = (v1.w - mu) * inv * w1.w + b1.w;
    float* orow = outf + (size_t)row * DIMD;
    ((float4*)orow)[lane]      = o0;
    ((float4*)orow)[lane + 64] = o1;
    bfraw* brow = outb + (size_t)row * DIMD;
    ushort4 s0, s1;
    s0.x = f2bf(o0.x); s0.y = f2bf(o0.y); s0.z = f2bf(o0.z); s0.w = f2bf(o0.w);
    s1.x = f2bf(o1.x); s1.y = f2bf(o1.y); s1.z = f2bf(o1.z); s1.w = f2bf(o1.w);
    ((ushort4*)brow)[lane]      = s0;
    ((ushort4*)brow)[lane + 64] = s1;
}

// ------------- transpose + convert: in fp32 [R][C] -> out bf16 [C][R] -------------
__global__ __launch_bounds__(256) void transpose_f32_bf16(const float* __restrict__ in,
                                                          bfraw* __restrict__ outp,
                                                          int R, int C) {
    __shared__ float tile[32][33];
    int c0 = blockIdx.x * 32, r0 = blockIdx.y * 32;
    int t = threadIdx.x;
    int tr = t >> 3, tc4 = (t & 7) * 4;
    float4 v = *(const float4*)&in[(size_t)(r0 + tr) * C + c0 + tc4];
    tile[tr][tc4 + 0] = v.x; tile[tr][tc4 + 1] = v.y;
    tile[tr][tc4 + 2] = v.z; tile[tr][tc4 + 3] = v.w;
    __syncthreads();
    ushort4 s;
    s.x = f2bf(tile[tc4 + 0][tr]);
    s.y = f2bf(tile[tc4 + 1][tr]);
    s.z = f2bf(tile[tc4 + 2][tr]);
    s.w = f2bf(tile[tc4 + 3][tr]);
    *(ushort4*)&outp[(size_t)(c0 + tr) * R + r0 + tc4] = s;
}

// ------------- bf16 MFMA GEMM: C[M,N] = epi(A[M,K] @ BT[N,K]^T + bias) -------------
// 128x128 tile, BK=32, 4 waves each 64x64 via 4x4 of 16x16x32 MFMA.
// EPI 0: silu -> bf16 out.  EPI 1: + resid -> fp32 out.
template <int EPI>
__global__ __launch_bounds__(256) void gemm_mfma(const bfraw* __restrict__ A,
                                                 const bfraw* __restrict__ BT,
                                                 const float* __restrict__ bias,
                                                 const float* __restrict__ resid,
                                                 void* __restrict__ Cv,
                                                 int M, int N, int K) {
    __shared__ __align__(16) bfraw As[128 * 32];   // [m][k], k contiguous
    __shared__ __align__(16) bfraw Bs[128 * 32];   // [n][k], k contiguous
    int t = threadIdx.x;
    int lane = t & 63, wid = t >> 6;
    int wm = wid >> 1, wn = wid & 1;
    int q = lane >> 4, mi = lane & 15;
    int row0 = blockIdx.y * 128, col0 = blockIdx.x * 128;
    f32x4 acc[4][4] = {};
    for (int k0 = 0; k0 < K; k0 += 32) {
        #pragma unroll
        for (int r = 0; r < 2; ++r) {
            int c = r * 256 + t;            // chunk id, 16B each; 512 chunks = 8KB tile
            const bfraw* g = A + (size_t)(row0 + (c >> 2)) * K + k0 + (c & 3) * 8;
            gload_lds16(g, As + (size_t)(r * 256 + wid * 64) * 8);
        }
        #pragma unroll
        for (int r = 0; r < 2; ++r) {
            int c = r * 256 + t;
            const bfraw* g = BT + (size_t)(col0 + (c >> 2)) * K + k0 + (c & 3) * 8;
            gload_lds16(g, Bs + (size_t)(r * 256 + wid * 64) * 8);
        }
        __syncthreads();
        bf16x8 af[4], bfg[4];
        #pragma unroll
        for (int i = 0; i < 4; ++i)
            af[i] = *(const bf16x8*)&As[(size_t)(wm * 64 + i * 16 + mi) * 32 + q * 8];
        #pragma unroll
        for (int j = 0; j < 4; ++j)
            bfg[j] = *(const bf16x8*)&Bs[(size_t)(wn * 64 + j * 16 + mi) * 32 + q * 8];
        #pragma unroll
        for (int i = 0; i < 4; ++i)
            #pragma unroll
            for (int j = 0; j < 4; ++j)
                acc[i][j] = __builtin_amdgcn_mfma_f32_16x16x32_bf16(af[i], bfg[j], acc[i][j], 0, 0, 0);
        __syncthreads();
    }
    #pragma unroll
    for (int i = 0; i < 4; ++i) {
        int rbase = row0 + wm * 64 + i * 16 + q * 4;
        #pragma unroll
        for (int j = 0; j < 4; ++j) {
            int col = col0 + wn * 64 + j * 16 + mi;
            float bv = bias[col];
            #pragma unroll
            for (int rg = 0; rg < 4; ++rg) {
                int row = rbase + rg;
                float z = acc[i][j][rg] + bv;
                if (EPI == 0) {
                    ((bfraw*)Cv)[(size_t)row * N + col] = f2bf(silu_f(z));
                } else {
                    ((float*)Cv)[(size_t)row * N + col] = z + resid[(size_t)row * N + col];
                }
            }
        }
    }
}

// ------------- fp32 inner-product tile helper (64x64 tile, 4x4/thread) -------------
__device__ __forceinline__ void mma_tile(const float As[KT][TS + 4],
                                         const float Bs[KT][TS + 4],
                                         float acc[4][4], int ty, int tx) {
    #pragma unroll
    for (int kk = 0; kk < KT; ++kk) {
        float a[4], bb[4];
        #pragma unroll
        for (int i = 0; i < 4; ++i) a[i] = As[kk][ty * 4 + i];
        #pragma unroll
        for (int j = 0; j < 4; ++j) bb[j] = Bs[kk][tx * 4 + j];
        #pragma unroll
        for (int i = 0; i < 4; ++i)
            #pragma unroll
            for (int j = 0; j < 4; ++j) acc[i][j] = fmaf(a[i], bb[j], acc[i][j]);
    }
}

// ------------- fp32 GEMM + bias + SiLU (used for qk only) -------------
__global__ __launch_bounds__(256) void gemm_bias_silu(const float* __restrict__ A,
                                                      const float* __restrict__ W,
                                                      const float* __restrict__ bias,
                                                      float* __restrict__ C,
                                                      int M, int N, int K) {
    __shared__ float As[KT][TS + 4];
    __shared__ float Bs[KT][TS + 4];
    int t = threadIdx.x;
    int tx = t & 15, ty = t >> 4;
    int row0 = blockIdx.y * TS, col0 = blockIdx.x * TS;
    float acc[4][4] = {};
    for (int k0 = 0; k0 < K; k0 += KT) {
        int r  = t >> 2;
        int c4 = (t & 3) << 2;
        float4 av = *(const float4*)&A[(size_t)(row0 + r) * K + k0 + c4];
        As[c4 + 0][r] = av.x; As[c4 + 1][r] = av.y;
        As[c4 + 2][r] = av.z; As[c4 + 3][r] = av.w;
        int br = t >> 4;
        int bc = (t & 15) << 2;
        float4 wv = *(const float4*)&W[(size_t)(k0 + br) * N + col0 + bc];
        *(float4*)&Bs[br][bc] = wv;
        __syncthreads();
        mma_tile(As, Bs, acc, ty, tx);
        __syncthreads();
    }
    #pragma unroll
    for (int i = 0; i < 4; ++i) {
        int row = row0 + ty * 4 + i;
        int col = col0 + tx * 4;
        float4 r;
        r.x = silu_f(acc[i][0] + bias[col + 0]);
        r.y = silu_f(acc[i][1] + bias[col + 1]);
        r.z = silu_f(acc[i][2] + bias[col + 2]);
        r.w = silu_f(acc[i][3] + bias[col + 3]);
        *(float4*)&C[(size_t)row * N + col] = r;
    }
}

// ------------- sim: attn[bg][i][j] = mask * relu(qq_i . qk_j / G)^2  (bf16 out) -------------
__global__ __launch_bounds__(256) void sim_kernel(const float* __restrict__ qk,
                                                  const float* __restrict__ gamma,
                                                  const float* __restrict__ beta,
                                                  bfraw* __restrict__ attn) {
    int bg   = blockIdx.z;
    int row0 = blockIdx.y * TS;
    int col0 = blockIdx.x * TS;
    if (col0 > row0) return;   // strictly-above-diagonal tiles are never read
    int t = threadIdx.x;
    int tx = t & 15, ty = t >> 4;
    bfraw* ag = attn + (size_t)bg * GRP * GRP;
    __shared__ float As[KT][TS + 4];
    __shared__ float Bs[KT][TS + 4];
    float acc[4][4] = {};
    for (int k0 = 0; k0 < QKD; k0 += KT) {
        int r  = t >> 2;
        int c4 = (t & 3) << 2;
        float4 g0 = *(const float4*)&gamma[0 * QKD + k0 + c4];
        float4 e0 = *(const float4*)&beta [0 * QKD + k0 + c4];
        float4 qv = *(const float4*)&qk[(size_t)(bg * GRP + row0 + r) * QKD + k0 + c4];
        As[c4 + 0][r] = qv.x * g0.x + e0.x;
        As[c4 + 1][r] = qv.y * g0.y + e0.y;
        As[c4 + 2][r] = qv.z * g0.z + e0.z;
        As[c4 + 3][r] = qv.w * g0.w + e0.w;
        float4 g2 = *(const float4*)&gamma[2 * QKD + k0 + c4];
        float4 e2 = *(const float4*)&beta [2 * QKD + k0 + c4];
        float4 kv = *(const float4*)&qk[(size_t)(bg * GRP + col0 + r) * QKD + k0 + c4];
        Bs[c4 + 0][r] = kv.x * g2.x + e2.x;
        Bs[c4 + 1][r] = kv.y * g2.y + e2.y;
        Bs[c4 + 2][r] = kv.z * g2.z + e2.z;
        Bs[c4 + 3][r] = kv.w * g2.w + e2.w;
        __syncthreads();
        mma_tile(As, Bs, acc, ty, tx);
        __syncthreads();
    }
    #pragma unroll
    for (int i = 0; i < 4; ++i) {
        int ig = row0 + ty * 4 + i;
        ushort4 r;
        bfraw* pr = &r.x;
        #pragma unroll
        for (int j = 0; j < 4; ++j) {
            int jg = col0 + tx * 4 + j;
            float s = acc[i][j] * (1.f / GRP);
            s = fmaxf(s, 0.f);
            s = s * s;
            pr[j] = (jg > ig) ? (bfraw)0 : f2bf(s);
        }
        *(ushort4*)&ag[(size_t)ig * GRP + col0 + tx * 4] = r;
    }
}

// ------------- kv[bg][d][e] = (1/G) * sum_n lk[n][d] * vv[n][e]  (fp32 out) -------------
__global__ __launch_bounds__(256) void kv_kernel(const float* __restrict__ qk,
                                                 const float* __restrict__ gamma,
                                                 const float* __restrict__ beta,
                                                 const bfraw* __restrict__ h,
                                                 float* __restrict__ kv) {
    int bg   = blockIdx.z;
    int d0   = blockIdx.y * TS;   // 0 or 64
    int col0 = blockIdx.x * TS;
    int t = threadIdx.x;
    int tx = t & 15, ty = t >> 4;
    __shared__ float As[KT][TS + 4];
    __shared__ float Bs[KT][TS + 4];
    float acc[4][4] = {};
    for (int n0 = 0; n0 < GRP; n0 += KT) {
        int c  = t >> 4;            // n offset 0..15
        int d4 = (t & 15) << 2;     // d offset 0..60
        float4 qv = *(const float4*)&qk[(size_t)(bg * GRP + n0 + c) * QKD + d0 + d4];
        float4 g3 = *(const float4*)&gamma[3 * QKD + d0 + d4];
        float4 e3 = *(const float4*)&beta [3 * QKD + d0 + d4];
        float4 avv = make_float4(qv.x * g3.x + e3.x, qv.y * g3.y + e3.y,
                                 qv.z * g3.z + e3.z, qv.w * g3.w + e3.w);
        *(float4*)&As[c][d4] = avv;
        int br = t >> 4;
        int bc = (t & 15) << 2;
        ushort4 wv = *(const ushort4*)&h[(size_t)(bg * GRP + n0 + br) * (2 * HIDD) + col0 + bc];
        Bs[br][bc + 0] = bf2f(wv.x); Bs[br][bc + 1] = bf2f(wv.y);
        Bs[br][bc + 2] = bf2f(wv.z); Bs[br][bc + 3] = bf2f(wv.w);
        __syncthreads();
        mma_tile(As, Bs, acc, ty, tx);
        __syncthreads();
    }
    #pragma unroll
    for (int i = 0; i < 4; ++i) {
        int d = d0 + ty * 4 + i;
        float4 r = make_float4(acc[i][0] * (1.f / GRP), acc[i][1] * (1.f / GRP),
                               acc[i][2] * (1.f / GRP), acc[i][3] * (1.f / GRP));
        *(float4*)&kv[(size_t)bg * QKD * HIDD + (size_t)d * HIDD + col0 + tx * 4] = r;
    }
}

// ------------- exclusive cumsum of kv over group dim (per batch) -------------
__global__ __launch_bounds__(256) void cumsum_kernel(float* __restrict__ kv) {
    int idx  = blockIdx.x * 256 + threadIdx.x;        // 0 .. 4*128*1024-1
    int bidx = idx >> 17;                             // / (128*1024)
    int off  = idx & 131071;
    float* p = kv + (size_t)bidx * (NGRP * QKD * HIDD) + off;
    float run = 0.f;
    #pragma unroll
    for (int g = 0; g < NGRP; ++g) {
        float tv = p[(size_t)g * QKD * HIDD];
        p[(size_t)g * QKD * HIDD] = run;
        run += tv;
    }
}

// ------------- gated[bg] = gate .* (attn@vv + lq@kv_ex)  (bf16 out) -------------
__global__ __launch_bounds__(256) void quadlin_kernel(const float* __restrict__ qk,
                                                      const float* __restrict__ gamma,
                                                      const float* __restrict__ beta,
                                                      const bfraw* __restrict__ attn,
                                                      const bfraw* __restrict__ h,
                                                      const float* __restrict__ kv,
                                                      bfraw* __restrict__ gated) {
    int bg   = blockIdx.z;
    int row0 = blockIdx.y * TS;
    int col0 = blockIdx.x * TS;
    int t = threadIdx.x;
    int tx = t & 15, ty = t >> 4;
    const bfraw* ag = attn + (size_t)bg * GRP * GRP;
    __shared__ float As[KT][TS + 4];
    __shared__ float Bs[KT][TS + 4];
    float acc[4][4] = {};
    int kmax = row0 + TS;
    for (int k0 = 0; k0 < kmax; k0 += KT) {
        int r  = t >> 2;
        int c4 = (t & 3) << 2;
        ushort4 av = *(const ushort4*)&ag[(size_t)(row0 + r) * GRP + k0 + c4];
        As[c4 + 0][r] = bf2f(av.x); As[c4 + 1][r] = bf2f(av.y);
        As[c4 + 2][r] = bf2f(av.z); As[c4 + 3][r] = bf2f(av.w);
        int br = t >> 4;
        int bc = (t & 15) << 2;
        ushort4 wv = *(const ushort4*)&h[(size_t)(bg * GRP + k0 + br) * (2 * HIDD) + col0 + bc];
        Bs[br][bc + 0] = bf2f(wv.x); Bs[br][bc + 1] = bf2f(wv.y);
        Bs[br][bc + 2] = bf2f(wv.z); Bs[br][bc + 3] = bf2f(wv.w);
        __syncthreads();
        mma_tile(As, Bs, acc, ty, tx);
        __syncthreads();
    }
    const float* kvg = kv + (size_t)bg * QKD * HIDD;
    for (int d0 = 0; d0 < QKD; d0 += KT) {
        int r  = t >> 2;
        int c4 = (t & 3) << 2;
        float4 g1 = *(const float4*)&gamma[1 * QKD + d0 + c4];
        float4 e1 = *(const float4*)&beta [1 * QKD + d0 + c4];
        float4 qv = *(const float4*)&qk[(size_t)(bg * GRP + row0 + r) * QKD + d0 + c4];
        As[c4 + 0][r] = qv.x * g1.x + e1.x;
        As[c4 + 1][r] = qv.y * g1.y + e1.y;
        As[c4 + 2][r] = qv.z * g1.z + e1.z;
        As[c4 + 3][r] = qv.w * g1.w + e1.w;
        int br = t >> 4;
        int bc = (t & 15) << 2;
        float4 wv = *(const float4*)&kvg[(size_t)(d0 + br) * HIDD + col0 + bc];
        *(float4*)&Bs[br][bc] = wv;
        __syncthreads();
        mma_tile(As, Bs, acc, ty, tx);
        __syncthreads();
    }
    #pragma unroll
    for (int i = 0; i < 4; ++i) {
        int row = bg * GRP + row0 + ty * 4 + i;
        int col = col0 + tx * 4;
        ushort4 gv = *(const ushort4*)&h[(size_t)row * (2 * HIDD) + HIDD + col];
        ushort4 s;
        s.x = f2bf(acc[i][0] * bf2f(gv.x));
        s.y = f2bf(acc[i][1] * bf2f(gv.y));
        s.z = f2bf(acc[i][2] * bf2f(gv.z));
        s.w = f2bf(acc[i][3] * bf2f(gv.w));
        *(ushort4*)&gated[(size_t)row * HIDD + col] = s;
    }
}

extern "C" void kernel_launch(void* const* d_in, const int* in_sizes, int n_in,
                              void* d_out, int out_size, void* d_ws, size_t ws_size,
                              hipStream_t stream) {
    const float* x     = (const float*)d_in[0];
    const float* ln_w  = (const float*)d_in[1];
    const float* ln_b  = (const float*)d_in[2];
    const float* Wh    = (const float*)d_in[3];
    const float* bh    = (const float*)d_in[4];
    const float* Wqk   = (const float*)d_in[5];
    const float* bqk   = (const float*)d_in[6];
    const float* gamma = (const float*)d_in[7];
    const float* beta  = (const float*)d_in[8];
    const float* Wo    = (const float*)d_in[9];
    const float* bo    = (const float*)d_in[10];
    float* out = (float*)d_out;

    // normed fp32 (32 MB) lives in d_out until final gemm overwrites it.
    float* normed = (float*)d_out;

    // ws layout (byte offsets), total 163 MB:
    char* wsb = (char*)d_ws;
    float* qk     = (float*)(wsb);                   //   8 MB fp32 [16384 x 128]
    bfraw* h      = (bfraw*)(wsb + 8388608);         //  64 MB bf16 [16384 x 2048]
    bfraw* attn   = (bfraw*)(wsb + 75497472);        //   8 MB bf16 [64 x 256 x 256]
    float* kv     = (float*)(wsb + 83886080);        //  32 MB fp32 [64 x 128 x 1024]
    bfraw* gated  = (bfraw*)(wsb + 117440512);       //  32 MB bf16 [16384 x 1024]
    bfraw* normb  = (bfraw*)(wsb + 150994944);       //  16 MB bf16 [16384 x 512]
    bfraw* WhT    = (bfraw*)(wsb + 167772160);       //   2 MB bf16 [2048 x 512]
    bfraw* WoT    = (bfraw*)(wsb + 169869312);       //   1 MB bf16 [512 x 1024]
    // end: 170,917,888 bytes

    // 0. weight transposes to bf16 [N][K]
    transpose_f32_bf16<<<dim3(2 * HIDD / 32, DIMD / 32), 256, 0, stream>>>(Wh, WhT, DIMD, 2 * HIDD);
    transpose_f32_bf16<<<dim3(DIMD / 32, HIDD / 32), 256, 0, stream>>>(Wo, WoT, HIDD, DIMD);
    // 1. LayerNorm -> normed fp32 (d_out) + bf16 copy
    ln_kernel<<<TROWS / 4, 256, 0, stream>>>(x, ln_w, ln_b, normed, normb);
    // 2. h = silu(normed @ Wh + bh)   [16384 x 2048] bf16 — MFMA
    gemm_mfma<0><<<dim3(2 * HIDD / 128, TROWS / 128), 256, 0, stream>>>(
        normb, WhT, bh, nullptr, (void*)h, TROWS, 2 * HIDD, DIMD);
    // 3. qk = silu(normed @ Wqk + bqk)  [16384 x 128] fp32
    gemm_bias_silu<<<dim3(QKD / TS, TROWS / TS), 256, 0, stream>>>(
        normed, Wqk, bqk, qk, TROWS, QKD, DIMD);
    // 4. attn = mask(relu(qq @ kk^T / G)^2)  per group (lower-tri tiles only)
    sim_kernel<<<dim3(GRP / TS, GRP / TS, BGRP), 256, 0, stream>>>(qk, gamma, beta, attn);
    // 5. kv = lk^T @ vv / G
    kv_kernel<<<dim3(HIDD / TS, QKD / TS, BGRP), 256, 0, stream>>>(qk, gamma, beta, h, kv);
    // 6. exclusive cumsum over groups
    cumsum_kernel<<<(BATCH * QKD * HIDD) / 256, 256, 0, stream>>>(kv);
    // 7. gated = gate .* (attn@vv + lq@kv_ex)
    quadlin_kernel<<<dim3(HIDD / TS, GRP / TS, BGRP), 256, 0, stream>>>(
        qk, gamma, beta, attn, h, kv, gated);
    // 8. out = gated @ Wo + bo + x — MFMA
    gemm_mfma<1><<<dim3(DIMD / 128, TROWS / 128), 256, 0, stream>>>(
        gated, WoT, bo, x, (void*)out, TROWS, DIMD, HIDD);
}

// Round 4
// 316.083 us; speedup vs baseline: 3.4306x; 1.6109x over previous
//
#include <hip/hip_runtime.h>
#include <math.h>

// FLASH (GAU-style) fused block. Round 3: ALL contractions on bf16 MFMA.
// b=4, n=4096, dim=512, hid=1024, qk=128, group=256.

#define BATCH 4
#define SEQ   4096
#define TROWS 16384      // BATCH*SEQ
#define DIMD  512
#define HIDD  1024
#define QKD   128
#define GRP   256
#define NGRP  16         // SEQ/GRP
#define BGRP  64         // BATCH*NGRP

typedef unsigned short bfraw;
typedef __attribute__((ext_vector_type(8))) short bf16x8;
typedef __attribute__((ext_vector_type(4))) float f32x4;

__device__ __forceinline__ float bf2f(bfraw u) {
    union { float f; unsigned int i; } c;
    c.i = ((unsigned int)u) << 16;
    return c.f;
}
__device__ __forceinline__ bfraw f2bf(float f) {
    unsigned int x = __float_as_uint(f);
    unsigned int r = (x + 0x7fffu + ((x >> 16) & 1u)) >> 16;   // RNE
    return (bfraw)r;
}
__device__ __forceinline__ float silu_f(float z) {
    return z / (1.f + __expf(-z));
}
__device__ __forceinline__ void gload_lds16(const void* g, void* l) {
    __builtin_amdgcn_global_load_lds(
        (const __attribute__((address_space(1))) unsigned int*)g,
        (__attribute__((address_space(3))) unsigned int*)l, 16, 0, 0);
}

// Stage a 128x32 bf16 tile (k contiguous, row stride = gstride elems) into LDS.
// gbase points at [tile_row0][k0]. Call with all 256 threads.
__device__ __forceinline__ void stage128(const bfraw* gbase, size_t gstride,
                                         bfraw* lds, int t, int wid) {
    #pragma unroll
    for (int r = 0; r < 2; ++r) {
        int c = r * 256 + t;                 // 16B chunk id; 4 chunks per row
        const bfraw* g = gbase + (size_t)(c >> 2) * gstride + (c & 3) * 8;
        gload_lds16(g, lds + (size_t)(r * 256 + wid * 64) * 8);
    }
}

// One BK=32 MFMA step on staged tiles (4 waves, each 64x64 = 4x4 frags).
__device__ __forceinline__ void mfma_step(const bfraw* As, const bfraw* Bs,
                                          f32x4 acc[4][4], int wm, int wn,
                                          int q, int mi) {
    bf16x8 af[4], bfg[4];
    #pragma unroll
    for (int i = 0; i < 4; ++i)
        af[i] = *(const bf16x8*)&As[(size_t)(wm * 64 + i * 16 + mi) * 32 + q * 8];
    #pragma unroll
    for (int j = 0; j < 4; ++j)
        bfg[j] = *(const bf16x8*)&Bs[(size_t)(wn * 64 + j * 16 + mi) * 32 + q * 8];
    #pragma unroll
    for (int i = 0; i < 4; ++i)
        #pragma unroll
        for (int j = 0; j < 4; ++j)
            acc[i][j] = __builtin_amdgcn_mfma_f32_16x16x32_bf16(af[i], bfg[j], acc[i][j], 0, 0, 0);
}

// ---------------- LayerNorm: one wave per row of 512; bf16 output ----------------
__global__ __launch_bounds__(256) void ln_kernel(const float* __restrict__ x,
                                                 const float* __restrict__ w,
                                                 const float* __restrict__ b,
                                                 bfraw* __restrict__ outb) {
    int row  = blockIdx.x * 4 + (threadIdx.x >> 6);
    int lane = threadIdx.x & 63;
    const float* xr = x + (size_t)row * DIMD;
    float4 v0 = ((const float4*)xr)[lane];
    float4 v1 = ((const float4*)xr)[lane + 64];
    float s  = v0.x + v0.y + v0.z + v0.w + v1.x + v1.y + v1.z + v1.w;
    float ss = v0.x*v0.x + v0.y*v0.y + v0.z*v0.z + v0.w*v0.w
             + v1.x*v1.x + v1.y*v1.y + v1.z*v1.z + v1.w*v1.w;
    #pragma unroll
    for (int off = 32; off; off >>= 1) {
        s  += __shfl_xor(s, off);
        ss += __shfl_xor(ss, off);
    }
    float mu  = s * (1.f / DIMD);
    float var = ss * (1.f / DIMD) - mu * mu;
    float inv = rsqrtf(var + 1e-5f);
    float4 w0 = ((const float4*)w)[lane],  w1 = ((const float4*)w)[lane + 64];
    float4 b0 = ((const float4*)b)[lane],  b1 = ((const float4*)b)[lane + 64];
    ushort4 s0, s1;
    s0.x = f2bf((v0.x - mu) * inv * w0.x + b0.x);
    s0.y = f2bf((v0.y - mu) * inv * w0.y + b0.y);
    s0.z = f2bf((v0.z - mu) * inv * w0.z + b0.z);
    s0.w = f2bf((v0.w - mu) * inv * w0.w + b0.w);
    s1.x = f2bf((v1.x - mu) * inv * w1.x + b1.x);
    s1.y = f2bf((v1.y - mu) * inv * w1.y + b1.y);
    s1.z = f2bf((v1.z - mu) * inv * w1.z + b1.z);
    s1.w = f2bf((v1.w - mu) * inv * w1.w + b1.w);
    bfraw* brow = outb + (size_t)row * DIMD;
    ((ushort4*)brow)[lane]      = s0;
    ((ushort4*)brow)[lane + 64] = s1;
}

// ------------- transpose + convert: in fp32 [R][C] -> out bf16 [C][R] -------------
__global__ __launch_bounds__(256) void transpose_f32_bf16(const float* __restrict__ in,
                                                          bfraw* __restrict__ outp,
                                                          int R, int C) {
    __shared__ float tile[32][33];
    int c0 = blockIdx.x * 32, r0 = blockIdx.y * 32;
    int t = threadIdx.x;
    int tr = t >> 3, tc4 = (t & 7) * 4;
    float4 v = *(const float4*)&in[(size_t)(r0 + tr) * C + c0 + tc4];
    tile[tr][tc4 + 0] = v.x; tile[tr][tc4 + 1] = v.y;
    tile[tr][tc4 + 2] = v.z; tile[tr][tc4 + 3] = v.w;
    __syncthreads();
    ushort4 s;
    s.x = f2bf(tile[tc4 + 0][tr]);
    s.y = f2bf(tile[tc4 + 1][tr]);
    s.z = f2bf(tile[tc4 + 2][tr]);
    s.w = f2bf(tile[tc4 + 3][tr]);
    *(ushort4*)&outp[(size_t)(c0 + tr) * R + r0 + tc4] = s;
}

// ------------- per-group bf16 transpose: out[bg][c][j] = in[(bg*256+j)*stride + c] -------------
// grid (256/32, C/32, 64)
__global__ __launch_bounds__(256) void transpose_grp(const bfraw* __restrict__ in,
                                                     bfraw* __restrict__ outp,
                                                     int stride, int C) {
    __shared__ bfraw tile[32][36];
    int bg = blockIdx.z;
    int j0 = blockIdx.x * 32, c0 = blockIdx.y * 32;
    int t = threadIdx.x;
    int tr = t >> 3, tc4 = (t & 7) * 4;
    ushort4 v = *(const ushort4*)&in[(size_t)(bg * GRP + j0 + tr) * stride + c0 + tc4];
    *(ushort4*)&tile[tr][tc4] = v;
    __syncthreads();
    ushort4 s;
    s.x = tile[tc4 + 0][tr];
    s.y = tile[tc4 + 1][tr];
    s.z = tile[tc4 + 2][tr];
    s.w = tile[tc4 + 3][tr];
    *(ushort4*)&outp[(size_t)bg * C * GRP + (size_t)(c0 + tr) * GRP + j0 + tc4] = s;
}

// ------------- bf16 MFMA GEMM: C[M,N] = epi(A[M,K] @ BT[N,K]^T + bias) -------------
// EPI 0: silu -> bf16 out.  EPI 1: + resid -> fp32 out.
template <int EPI>
__global__ __launch_bounds__(256) void gemm_mfma(const bfraw* __restrict__ A,
                                                 const bfraw* __restrict__ BT,
                                                 const float* __restrict__ bias,
                                                 const float* __restrict__ resid,
                                                 void* __restrict__ Cv,
                                                 int M, int N, int K) {
    __shared__ __align__(16) bfraw As[128 * 32];
    __shared__ __align__(16) bfraw Bs[128 * 32];
    int t = threadIdx.x;
    int lane = t & 63, wid = t >> 6;
    int wm = wid >> 1, wn = wid & 1;
    int q = lane >> 4, mi = lane & 15;
    int row0 = blockIdx.y * 128, col0 = blockIdx.x * 128;
    f32x4 acc[4][4] = {};
    for (int k0 = 0; k0 < K; k0 += 32) {
        stage128(A + (size_t)row0 * K + k0, K, As, t, wid);
        stage128(BT + (size_t)col0 * K + k0, K, Bs, t, wid);
        __syncthreads();
        mfma_step(As, Bs, acc, wm, wn, q, mi);
        __syncthreads();
    }
    #pragma unroll
    for (int i = 0; i < 4; ++i) {
        int rbase = row0 + wm * 64 + i * 16 + q * 4;
        #pragma unroll
        for (int j = 0; j < 4; ++j) {
            int col = col0 + wn * 64 + j * 16 + mi;
            float bv = bias[col];
            #pragma unroll
            for (int rg = 0; rg < 4; ++rg) {
                int row = rbase + rg;
                float z = acc[i][j][rg] + bv;
                if (EPI == 0) {
                    ((bfraw*)Cv)[(size_t)row * N + col] = f2bf(silu_f(z));
                } else {
                    ((float*)Cv)[(size_t)row * N + col] = z + resid[(size_t)row * N + col];
                }
            }
        }
    }
}

// ------------- qk GEMM: z=silu(normb@WqkT + bqk), emit 4 head-projected bf16 arrays -------------
// grid (1, TROWS/128). N = 128.
__global__ __launch_bounds__(256) void qk_mfma(const bfraw* __restrict__ A,
                                               const bfraw* __restrict__ BT,
                                               const float* __restrict__ bqk,
                                               const float* __restrict__ gamma,
                                               const float* __restrict__ beta,
                                               bfraw* __restrict__ qq,
                                               bfraw* __restrict__ lq,
                                               bfraw* __restrict__ kk,
                                               bfraw* __restrict__ lk) {
    __shared__ __align__(16) bfraw As[128 * 32];
    __shared__ __align__(16) bfraw Bs[128 * 32];
    int t = threadIdx.x;
    int lane = t & 63, wid = t >> 6;
    int wm = wid >> 1, wn = wid & 1;
    int q = lane >> 4, mi = lane & 15;
    int row0 = blockIdx.y * 128;
    f32x4 acc[4][4] = {};
    for (int k0 = 0; k0 < DIMD; k0 += 32) {
        stage128(A + (size_t)row0 * DIMD + k0, DIMD, As, t, wid);
        stage128(BT + (size_t)k0, DIMD, Bs, t, wid);
        __syncthreads();
        mfma_step(As, Bs, acc, wm, wn, q, mi);
        __syncthreads();
    }
    #pragma unroll
    for (int i = 0; i < 4; ++i) {
        int rbase = row0 + wm * 64 + i * 16 + q * 4;
        #pragma unroll
        for (int j = 0; j < 4; ++j) {
            int col = wn * 64 + j * 16 + mi;
            float bv = bqk[col];
            float g0 = gamma[0 * QKD + col], e0 = beta[0 * QKD + col];
            float g1 = gamma[1 * QKD + col], e1 = beta[1 * QKD + col];
            float g2 = gamma[2 * QKD + col], e2 = beta[2 * QKD + col];
            float g3 = gamma[3 * QKD + col], e3 = beta[3 * QKD + col];
            #pragma unroll
            for (int rg = 0; rg < 4; ++rg) {
                int row = rbase + rg;
                float z = silu_f(acc[i][j][rg] + bv);
                size_t o = (size_t)row * QKD + col;
                qq[o] = f2bf(z * g0 + e0);
                lq[o] = f2bf(z * g1 + e1);
                kk[o] = f2bf(z * g2 + e2);
                lk[o] = f2bf(z * g3 + e3);
            }
        }
    }
}

// ------------- sim: attn[bg][i][j] = mask * relu(qq_i . kk_j / G)^2  (bf16 out) -------------
// grid (3, 64): tile id 0->(0,0) 1->(1,0) 2->(1,1) of 128x128 tiles.
__global__ __launch_bounds__(256) void sim_mfma(const bfraw* __restrict__ qq,
                                                const bfraw* __restrict__ kk,
                                                bfraw* __restrict__ attn) {
    int bg = blockIdx.y;
    int tid = blockIdx.x;
    int ry = (tid == 0) ? 0 : 1;
    int rx = (tid == 2) ? 1 : 0;
    int row0 = ry * 128, col0 = rx * 128;
    __shared__ __align__(16) bfraw As[128 * 32];
    __shared__ __align__(16) bfraw Bs[128 * 32];
    int t = threadIdx.x;
    int lane = t & 63, wid = t >> 6;
    int wm = wid >> 1, wn = wid & 1;
    int q = lane >> 4, mi = lane & 15;
    f32x4 acc[4][4] = {};
    const bfraw* Ag = qq + (size_t)(bg * GRP + row0) * QKD;
    const bfraw* Bg = kk + (size_t)(bg * GRP + col0) * QKD;
    for (int k0 = 0; k0 < QKD; k0 += 32) {
        stage128(Ag + k0, QKD, As, t, wid);
        stage128(Bg + k0, QKD, Bs, t, wid);
        __syncthreads();
        mfma_step(As, Bs, acc, wm, wn, q, mi);
        __syncthreads();
    }
    bfraw* ag = attn + (size_t)bg * GRP * GRP;
    #pragma unroll
    for (int i = 0; i < 4; ++i) {
        int rbase = row0 + wm * 64 + i * 16 + q * 4;
        #pragma unroll
        for (int j = 0; j < 4; ++j) {
            int colg = col0 + wn * 64 + j * 16 + mi;
            #pragma unroll
            for (int rg = 0; rg < 4; ++rg) {
                int rowg = rbase + rg;
                float s = acc[i][j][rg] * (1.f / GRP);
                s = fmaxf(s, 0.f);
                s = s * s;
                ag[(size_t)rowg * GRP + colg] = (colg > rowg) ? (bfraw)0 : f2bf(s);
            }
        }
    }
}

// ------------- kvT_raw[bg][e][d] = sum_j vT[bg][e][j] * lkT[bg][d][j]  (bf16 out) -------------
// grid (1, 8, 64): M=1024 (e), N=128 (d), K=256 (j).
__global__ __launch_bounds__(256) void kv_mfma(const bfraw* __restrict__ vT,
                                               const bfraw* __restrict__ lkT,
                                               bfraw* __restrict__ kvT_raw) {
    int bg = blockIdx.z;
    int row0 = blockIdx.y * 128;
    __shared__ __align__(16) bfraw As[128 * 32];
    __shared__ __align__(16) bfraw Bs[128 * 32];
    int t = threadIdx.x;
    int lane = t & 63, wid = t >> 6;
    int wm = wid >> 1, wn = wid & 1;
    int q = lane >> 4, mi = lane & 15;
    f32x4 acc[4][4] = {};
    const bfraw* Ag = vT + (size_t)bg * HIDD * GRP + (size_t)row0 * GRP;
    const bfraw* Bg = lkT + (size_t)bg * QKD * GRP;
    for (int k0 = 0; k0 < GRP; k0 += 32) {
        stage128(Ag + k0, GRP, As, t, wid);
        stage128(Bg + k0, GRP, Bs, t, wid);
        __syncthreads();
        mfma_step(As, Bs, acc, wm, wn, q, mi);
        __syncthreads();
    }
    bfraw* outg = kvT_raw + (size_t)bg * HIDD * QKD;
    #pragma unroll
    for (int i = 0; i < 4; ++i) {
        int rbase = row0 + wm * 64 + i * 16 + q * 4;
        #pragma unroll
        for (int j = 0; j < 4; ++j) {
            int col = wn * 64 + j * 16 + mi;
            #pragma unroll
            for (int rg = 0; rg < 4; ++rg)
                outg[(size_t)(rbase + rg) * QKD + col] = f2bf(acc[i][j][rg]);
        }
    }
}

// ------------- exclusive cumsum over groups: kvT_ex[bg][e][d], incl /G scale -------------
__global__ __launch_bounds__(256) void cumsum2_kernel(const bfraw* __restrict__ raw,
                                                      bfraw* __restrict__ ex) {
    int idx = blockIdx.x * 256 + threadIdx.x;   // 0 .. 4*1024*128-1
    int b = idx >> 17;                          // / (1024*128)
    int r = idx & 131071;
    const bfraw* rp = raw + (size_t)b * NGRP * 131072 + r;
    bfraw* ep = ex + (size_t)b * NGRP * 131072 + r;
    float run = 0.f;
    #pragma unroll
    for (int g = 0; g < NGRP; ++g) {
        ep[(size_t)g * 131072] = f2bf(run);
        run += bf2f(rp[(size_t)g * 131072]) * (1.f / GRP);
    }
}

// ------------- gated = gate .* (attn@vv + lq@kv_ex)  (bf16 out) -------------
// grid (8 e-tiles, 2 row-tiles, 64 groups)
__global__ __launch_bounds__(256) void quadlin_mfma(const bfraw* __restrict__ attn,
                                                    const bfraw* __restrict__ vT,
                                                    const bfraw* __restrict__ lq,
                                                    const bfraw* __restrict__ kvT_ex,
                                                    const bfraw* __restrict__ h,
                                                    bfraw* __restrict__ gated) {
    int bg = blockIdx.z;
    int row0 = blockIdx.y * 128;
    int col0 = blockIdx.x * 128;
    __shared__ __align__(16) bfraw As[128 * 32];
    __shared__ __align__(16) bfraw Bs[128 * 32];
    int t = threadIdx.x;
    int lane = t & 63, wid = t >> 6;
    int wm = wid >> 1, wn = wid & 1;
    int q = lane >> 4, mi = lane & 15;
    f32x4 acc[4][4] = {};
    // Part 1: quadratic. A = attn rows (stride 256), BT = vT rows (stride 256).
    const bfraw* Ag = attn + (size_t)bg * GRP * GRP + (size_t)row0 * GRP;
    const bfraw* Bg = vT + (size_t)bg * HIDD * GRP + (size_t)col0 * GRP;
    int kmax = row0 + 128;     // causal: attn[i][j]=0 for j>i
    for (int k0 = 0; k0 < kmax; k0 += 32) {
        stage128(Ag + k0, GRP, As, t, wid);
        stage128(Bg + k0, GRP, Bs, t, wid);
        __syncthreads();
        mfma_step(As, Bs, acc, wm, wn, q, mi);
        __syncthreads();
    }
    // Part 2: linear. A = lq rows (stride 128), BT = kvT_ex rows (stride 128).
    const bfraw* Ag2 = lq + (size_t)(bg * GRP + row0) * QKD;
    const bfraw* Bg2 = kvT_ex + (size_t)bg * HIDD * QKD + (size_t)col0 * QKD;
    for (int k0 = 0; k0 < QKD; k0 += 32) {
        stage128(Ag2 + k0, QKD, As, t, wid);
        stage128(Bg2 + k0, QKD, Bs, t, wid);
        __syncthreads();
        mfma_step(As, Bs, acc, wm, wn, q, mi);
        __syncthreads();
    }
    // Epilogue: gate and store.
    #pragma unroll
    for (int i = 0; i < 4; ++i) {
        int rbase = row0 + wm * 64 + i * 16 + q * 4;
        #pragma unroll
        for (int j = 0; j < 4; ++j) {
            int col = col0 + wn * 64 + j * 16 + mi;
            #pragma unroll
            for (int rg = 0; rg < 4; ++rg) {
                size_t grow = (size_t)bg * GRP + rbase + rg;
                float gate = bf2f(h[grow * (2 * HIDD) + HIDD + col]);
                gated[grow * HIDD + col] = f2bf(acc[i][j][rg] * gate);
            }
        }
    }
}

extern "C" void kernel_launch(void* const* d_in, const int* in_sizes, int n_in,
                              void* d_out, int out_size, void* d_ws, size_t ws_size,
                              hipStream_t stream) {
    const float* x     = (const float*)d_in[0];
    const float* ln_w  = (const float*)d_in[1];
    const float* ln_b  = (const float*)d_in[2];
    const float* Wh    = (const float*)d_in[3];
    const float* bh    = (const float*)d_in[4];
    const float* Wqk   = (const float*)d_in[5];
    const float* bqk   = (const float*)d_in[6];
    const float* gamma = (const float*)d_in[7];
    const float* beta  = (const float*)d_in[8];
    const float* Wo    = (const float*)d_in[9];
    const float* bo    = (const float*)d_in[10];
    float* out = (float*)d_out;

    // d_out (32 MiB) hosts short-lived buffers; final GEMM overwrites it last.
    char* outb_ = (char*)d_out;
    bfraw* attn = (bfraw*)(outb_);                    //  8 MiB [64][256][256]
    bfraw* lq   = (bfraw*)(outb_ + 8388608);          //  4 MiB [16384][128]
    bfraw* WhT  = (bfraw*)(outb_ + 12582912);         //  2 MiB [2048][512]

    // ws layout (MiB offsets), total 161.1 MiB:
    char* wsb = (char*)d_ws;
    bfraw* h       = (bfraw*)(wsb);                   // 64 MiB [16384][2048]
    bfraw* vT      = (bfraw*)(wsb + 67108864);        // 32 MiB [64][1024][256]
    bfraw* gated   = (bfraw*)(wsb + 100663296);       // 32 MiB [16384][1024]
    //   overlaid inside gated region (all dead before quadlin writes gated):
    bfraw* qq      = (bfraw*)(wsb + 100663296);       //  4 MiB [16384][128]
    bfraw* kk      = (bfraw*)(wsb + 104857600);       //  4 MiB
    bfraw* lk      = (bfraw*)(wsb + 109051904);       //  4 MiB
    bfraw* lkT     = (bfraw*)(wsb + 113246208);       //  4 MiB [64][128][256]
    bfraw* kvT_ex  = (bfraw*)(wsb + 134217728);       // 16 MiB [64][1024][128]
    bfraw* normb   = (bfraw*)(wsb + 150994944);       // 16 MiB [16384][512]
    bfraw* kvT_raw = (bfraw*)(wsb + 150994944);       // 16 MiB (overlays normb; normb dead)
    bfraw* WoT     = (bfraw*)(wsb + 167772160);       //  1 MiB [512][1024]
    bfraw* WqkT    = (bfraw*)(wsb + 168820736);       //  128 KiB [128][512]
    // end: 168,951,808 bytes = 161.1 MiB

    // 0-2. weight transposes to bf16 [N][K]
    transpose_f32_bf16<<<dim3(2 * HIDD / 32, DIMD / 32), 256, 0, stream>>>(Wh, WhT, DIMD, 2 * HIDD);
    transpose_f32_bf16<<<dim3(DIMD / 32, HIDD / 32), 256, 0, stream>>>(Wo, WoT, HIDD, DIMD);
    transpose_f32_bf16<<<dim3(QKD / 32, DIMD / 32), 256, 0, stream>>>(Wqk, WqkT, DIMD, QKD);
    // 3. LayerNorm -> normb bf16
    ln_kernel<<<TROWS / 4, 256, 0, stream>>>(x, ln_w, ln_b, normb);
    // 4. h = silu(normb @ Wh + bh)   [16384 x 2048] bf16 — MFMA
    gemm_mfma<0><<<dim3(2 * HIDD / 128, TROWS / 128), 256, 0, stream>>>(
        normb, WhT, bh, nullptr, (void*)h, TROWS, 2 * HIDD, DIMD);
    // 5. qk heads: qq/lq/kk/lk = silu(normb @ Wqk + bqk)*gamma_i+beta_i — MFMA
    qk_mfma<<<dim3(1, TROWS / 128), 256, 0, stream>>>(
        normb, WqkT, bqk, gamma, beta, qq, lq, kk, lk);
    // 6. vT[bg][e][j] = v[bg*256+j][e]  (v = h[:, :1024])
    transpose_grp<<<dim3(GRP / 32, HIDD / 32, BGRP), 256, 0, stream>>>(h, vT, 2 * HIDD, HIDD);
    // 7. lkT[bg][d][j] = lk[bg*256+j][d]
    transpose_grp<<<dim3(GRP / 32, QKD / 32, BGRP), 256, 0, stream>>>(lk, lkT, QKD, QKD);
    // 8. attn = mask(relu(qq @ kk^T / G)^2)  (3 lower tiles per group) — MFMA
    sim_mfma<<<dim3(3, BGRP), 256, 0, stream>>>(qq, kk, attn);
    // 9. kvT_raw[e][d] = sum_j vT[e][j]*lkT[d][j] — MFMA
    kv_mfma<<<dim3(1, HIDD / 128, BGRP), 256, 0, stream>>>(vT, lkT, kvT_raw);
    // 10. exclusive cumsum over groups (with /G) -> kvT_ex bf16
    cumsum2_kernel<<<(BATCH * QKD * HIDD) / 256, 256, 0, stream>>>(kvT_raw, kvT_ex);
    // 11. gated = gate .* (attn@vv + lq@kv_ex) — MFMA
    quadlin_mfma<<<dim3(HIDD / 128, GRP / 128, BGRP), 256, 0, stream>>>(
        attn, vT, lq, kvT_ex, h, gated);
    // 12. out = gated @ Wo + bo + x — MFMA
    gemm_mfma<1><<<dim3(DIMD / 128, TROWS / 128), 256, 0, stream>>>(
        gated, WoT, bo, x, (void*)out, TROWS, DIMD, HIDD);
}

// Round 5
// 301.799 us; speedup vs baseline: 3.5930x; 1.0473x over previous
//
#include <hip/hip_runtime.h>
#include <math.h>

// FLASH (GAU-style) fused block. Round 4: LDS-vectorized epilogues,
// transposes fused into producers (v stored only as vT, lk only as lkT).
// b=4, n=4096, dim=512, hid=1024, qk=128, group=256.

#define BATCH 4
#define SEQ   4096
#define TROWS 16384      // BATCH*SEQ
#define DIMD  512
#define HIDD  1024
#define QKD   128
#define GRP   256
#define NGRP  16         // SEQ/GRP
#define BGRP  64         // BATCH*NGRP
#define EPIW  132        // padded LDS epilogue row stride (f32)

typedef unsigned short bfraw;
typedef __attribute__((ext_vector_type(8))) short bf16x8;
typedef __attribute__((ext_vector_type(8))) unsigned short u16x8;
typedef __attribute__((ext_vector_type(4))) float f32x4;

__device__ __forceinline__ float bf2f(bfraw u) {
    union { float f; unsigned int i; } c;
    c.i = ((unsigned int)u) << 16;
    return c.f;
}
__device__ __forceinline__ bfraw f2bf(float f) {
    unsigned int x = __float_as_uint(f);
    unsigned int r = (x + 0x7fffu + ((x >> 16) & 1u)) >> 16;   // RNE
    return (bfraw)r;
}
__device__ __forceinline__ float silu_f(float z) {
    return z / (1.f + __expf(-z));
}
__device__ __forceinline__ void gload_lds16(const void* g, void* l) {
    __builtin_amdgcn_global_load_lds(
        (const __attribute__((address_space(1))) unsigned int*)g,
        (__attribute__((address_space(3))) unsigned int*)l, 16, 0, 0);
}

// Stage a 128x32 bf16 tile (k contiguous, row stride = gstride elems) into LDS.
__device__ __forceinline__ void stage128(const bfraw* gbase, size_t gstride,
                                         bfraw* lds, int t, int wid) {
    #pragma unroll
    for (int r = 0; r < 2; ++r) {
        int c = r * 256 + t;                 // 16B chunk id; 4 chunks per row
        const bfraw* g = gbase + (size_t)(c >> 2) * gstride + (c & 3) * 8;
        gload_lds16(g, lds + (size_t)(r * 256 + wid * 64) * 8);
    }
}

// One BK=32 MFMA step on staged tiles (4 waves, each 64x64 = 4x4 frags).
__device__ __forceinline__ void mfma_step(const bfraw* As, const bfraw* Bs,
                                          f32x4 acc[4][4], int wm, int wn,
                                          int q, int mi) {
    bf16x8 af[4], bfg[4];
    #pragma unroll
    for (int i = 0; i < 4; ++i)
        af[i] = *(const bf16x8*)&As[(size_t)(wm * 64 + i * 16 + mi) * 32 + q * 8];
    #pragma unroll
    for (int j = 0; j < 4; ++j)
        bfg[j] = *(const bf16x8*)&Bs[(size_t)(wn * 64 + j * 16 + mi) * 32 + q * 8];
    #pragma unroll
    for (int i = 0; i < 4; ++i)
        #pragma unroll
        for (int j = 0; j < 4; ++j)
            acc[i][j] = __builtin_amdgcn_mfma_f32_16x16x32_bf16(af[i], bfg[j], acc[i][j], 0, 0, 0);
}

// Row-major readback helper: thread t covers LDS row lr=t>>3, cols (t&7)*16..+15.
// Returns the pass-local -> tile-local row mapping.
__device__ __forceinline__ int epi_row(int p, int lr) {
    return (lr < 16) ? (p * 16 + lr) : (64 + p * 16 + (lr - 16));
}

// ---------------- LayerNorm: one wave per row of 512; bf16 output ----------------
__global__ __launch_bounds__(256) void ln_kernel(const float* __restrict__ x,
                                                 const float* __restrict__ w,
                                                 const float* __restrict__ b,
                                                 bfraw* __restrict__ outb) {
    int row  = blockIdx.x * 4 + (threadIdx.x >> 6);
    int lane = threadIdx.x & 63;
    const float* xr = x + (size_t)row * DIMD;
    float4 v0 = ((const float4*)xr)[lane];
    float4 v1 = ((const float4*)xr)[lane + 64];
    float s  = v0.x + v0.y + v0.z + v0.w + v1.x + v1.y + v1.z + v1.w;
    float ss = v0.x*v0.x + v0.y*v0.y + v0.z*v0.z + v0.w*v0.w
             + v1.x*v1.x + v1.y*v1.y + v1.z*v1.z + v1.w*v1.w;
    #pragma unroll
    for (int off = 32; off; off >>= 1) {
        s  += __shfl_xor(s, off);
        ss += __shfl_xor(ss, off);
    }
    float mu  = s * (1.f / DIMD);
    float var = ss * (1.f / DIMD) - mu * mu;
    float inv = rsqrtf(var + 1e-5f);
    float4 w0 = ((const float4*)w)[lane],  w1 = ((const float4*)w)[lane + 64];
    float4 b0 = ((const float4*)b)[lane],  b1 = ((const float4*)b)[lane + 64];
    ushort4 s0, s1;
    s0.x = f2bf((v0.x - mu) * inv * w0.x + b0.x);
    s0.y = f2bf((v0.y - mu) * inv * w0.y + b0.y);
    s0.z = f2bf((v0.z - mu) * inv * w0.z + b0.z);
    s0.w = f2bf((v0.w - mu) * inv * w0.w + b0.w);
    s1.x = f2bf((v1.x - mu) * inv * w1.x + b1.x);
    s1.y = f2bf((v1.y - mu) * inv * w1.y + b1.y);
    s1.z = f2bf((v1.z - mu) * inv * w1.z + b1.z);
    s1.w = f2bf((v1.w - mu) * inv * w1.w + b1.w);
    bfraw* brow = outb + (size_t)row * DIMD;
    ((ushort4*)brow)[lane]      = s0;
    ((ushort4*)brow)[lane + 64] = s1;
}

// ------------- transpose + convert: in fp32 [R][C] -> out bf16 [C][R] -------------
__global__ __launch_bounds__(256) void transpose_f32_bf16(const float* __restrict__ in,
                                                          bfraw* __restrict__ outp,
                                                          int R, int C) {
    __shared__ float tile[32][33];
    int c0 = blockIdx.x * 32, r0 = blockIdx.y * 32;
    int t = threadIdx.x;
    int tr = t >> 3, tc4 = (t & 7) * 4;
    float4 v = *(const float4*)&in[(size_t)(r0 + tr) * C + c0 + tc4];
    tile[tr][tc4 + 0] = v.x; tile[tr][tc4 + 1] = v.y;
    tile[tr][tc4 + 2] = v.z; tile[tr][tc4 + 3] = v.w;
    __syncthreads();
    ushort4 s;
    s.x = f2bf(tile[tc4 + 0][tr]);
    s.y = f2bf(tile[tc4 + 1][tr]);
    s.z = f2bf(tile[tc4 + 2][tr]);
    s.w = f2bf(tile[tc4 + 3][tr]);
    *(ushort4*)&outp[(size_t)(c0 + tr) * R + r0 + tc4] = s;
}

// ------------- h GEMM: z = silu(normb @ WhT^T + bh).
// cols <1024 (v): write vT[bg][e][j].  cols >=1024: write gate[row][e] row-major.
__global__ __launch_bounds__(256) void gemm_h(const bfraw* __restrict__ A,
                                              const bfraw* __restrict__ BT,
                                              const float* __restrict__ bias,
                                              bfraw* __restrict__ vT,
                                              bfraw* __restrict__ gate) {
    __shared__ __align__(16) char smem_[16896];
    bfraw* As = (bfraw*)smem_;
    bfraw* Bs = As + 128 * 32;
    float* epi = (float*)smem_;
    int t = threadIdx.x;
    int lane = t & 63, wid = t >> 6;
    int wm = wid >> 1, wn = wid & 1;
    int q = lane >> 4, mi = lane & 15;
    int row0 = blockIdx.y * 128, col0 = blockIdx.x * 128;
    f32x4 acc[4][4] = {};
    for (int k0 = 0; k0 < DIMD; k0 += 32) {
        stage128(A + (size_t)row0 * DIMD + k0, DIMD, As, t, wid);
        stage128(BT + (size_t)col0 * DIMD + k0, DIMD, Bs, t, wid);
        __syncthreads();
        mfma_step(As, Bs, acc, wm, wn, q, mi);
        __syncthreads();
    }
    bool vpath = (col0 < HIDD);
    int bg = row0 >> 8;
    #pragma unroll
    for (int p = 0; p < 4; ++p) {
        #pragma unroll
        for (int j = 0; j < 4; ++j) {
            float bv = bias[col0 + wn * 64 + j * 16 + mi];
            #pragma unroll
            for (int rg = 0; rg < 4; ++rg)
                epi[(wm * 16 + q * 4 + rg) * EPIW + wn * 64 + j * 16 + mi] =
                    silu_f(acc[p][j][rg] + bv);
        }
        __syncthreads();
        if (vpath) {
            int c = t >> 1, half = t & 1;
            int e = col0 + c;
            int j0 = (row0 & 255) + half * 64 + p * 16;
            bfraw* dst = vT + ((size_t)bg * HIDD + e) * GRP + j0;
            u16x8 s0, s1;
            #pragma unroll
            for (int k = 0; k < 8; ++k) s0[k] = f2bf(epi[(half * 16 + k) * EPIW + c]);
            #pragma unroll
            for (int k = 0; k < 8; ++k) s1[k] = f2bf(epi[(half * 16 + 8 + k) * EPIW + c]);
            *(u16x8*)dst = s0;
            *(u16x8*)(dst + 8) = s1;
        } else {
            int lr = t >> 3, c0t = (t & 7) * 16;
            int gr = row0 + epi_row(p, lr);
            const float* src = &epi[lr * EPIW + c0t];
            u16x8 s0, s1;
            #pragma unroll
            for (int k = 0; k < 8; ++k) s0[k] = f2bf(src[k]);
            #pragma unroll
            for (int k = 0; k < 8; ++k) s1[k] = f2bf(src[8 + k]);
            bfraw* dst = gate + (size_t)gr * HIDD + (col0 - HIDD) + c0t;
            *(u16x8*)dst = s0;
            *(u16x8*)(dst + 8) = s1;
        }
        __syncthreads();
    }
}

// ------------- qk GEMM: z = silu(normb @ WqkT^T + bqk); emit qq/lq/kk row-major + lkT.
__global__ __launch_bounds__(256) void qk_mfma(const bfraw* __restrict__ A,
                                               const bfraw* __restrict__ BT,
                                               const float* __restrict__ bqk,
                                               const float* __restrict__ gamma,
                                               const float* __restrict__ beta,
                                               bfraw* __restrict__ qq,
                                               bfraw* __restrict__ lq,
                                               bfraw* __restrict__ kk,
                                               bfraw* __restrict__ lkT) {
    __shared__ __align__(16) char smem_[16896];
    bfraw* As = (bfraw*)smem_;
    bfraw* Bs = As + 128 * 32;
    float* epi = (float*)smem_;
    int t = threadIdx.x;
    int lane = t & 63, wid = t >> 6;
    int wm = wid >> 1, wn = wid & 1;
    int q = lane >> 4, mi = lane & 15;
    int row0 = blockIdx.y * 128;
    f32x4 acc[4][4] = {};
    for (int k0 = 0; k0 < DIMD; k0 += 32) {
        stage128(A + (size_t)row0 * DIMD + k0, DIMD, As, t, wid);
        stage128(BT + (size_t)k0, DIMD, Bs, t, wid);
        __syncthreads();
        mfma_step(As, Bs, acc, wm, wn, q, mi);
        __syncthreads();
    }
    int bg = row0 >> 8;
    #pragma unroll
    for (int p = 0; p < 4; ++p) {
        #pragma unroll
        for (int j = 0; j < 4; ++j) {
            float bv = bqk[wn * 64 + j * 16 + mi];
            #pragma unroll
            for (int rg = 0; rg < 4; ++rg)
                epi[(wm * 16 + q * 4 + rg) * EPIW + wn * 64 + j * 16 + mi] =
                    silu_f(acc[p][j][rg] + bv);
        }
        __syncthreads();
        // row-major: qq, lq, kk
        {
            int lr = t >> 3, c0t = (t & 7) * 16;
            int gr = row0 + epi_row(p, lr);
            const float* src = &epi[lr * EPIW + c0t];
            float z[16];
            #pragma unroll
            for (int k = 0; k < 16; ++k) z[k] = src[k];
            #pragma unroll
            for (int hd = 0; hd < 3; ++hd) {        // 0:qq 1:lq 2:kk
                bfraw* arr = (hd == 0) ? qq : (hd == 1) ? lq : kk;
                const float* gp = gamma + hd * QKD + c0t;
                const float* ep = beta  + hd * QKD + c0t;
                u16x8 s0, s1;
                #pragma unroll
                for (int k = 0; k < 8; ++k) s0[k] = f2bf(z[k] * gp[k] + ep[k]);
                #pragma unroll
                for (int k = 0; k < 8; ++k) s1[k] = f2bf(z[8 + k] * gp[8 + k] + ep[8 + k]);
                bfraw* dst = arr + (size_t)gr * QKD + c0t;
                *(u16x8*)dst = s0;
                *(u16x8*)(dst + 8) = s1;
            }
        }
        // transposed: lkT (head 3)
        {
            int c = t >> 1, half = t & 1;
            float g3 = gamma[3 * QKD + c], e3 = beta[3 * QKD + c];
            int j0 = (row0 & 255) + half * 64 + p * 16;
            bfraw* dst = lkT + ((size_t)bg * QKD + c) * GRP + j0;
            u16x8 s0, s1;
            #pragma unroll
            for (int k = 0; k < 8; ++k)
                s0[k] = f2bf(epi[(half * 16 + k) * EPIW + c] * g3 + e3);
            #pragma unroll
            for (int k = 0; k < 8; ++k)
                s1[k] = f2bf(epi[(half * 16 + 8 + k) * EPIW + c] * g3 + e3);
            *(u16x8*)dst = s0;
            *(u16x8*)(dst + 8) = s1;
        }
        __syncthreads();
    }
}

// ------------- sim: attn[bg][i][j] = mask * relu(qq_i . kk_j / G)^2  (bf16 out) -------------
// grid (3, 64): tile id 0->(0,0) 1->(1,0) 2->(1,1) of 128x128 tiles.
__global__ __launch_bounds__(256) void sim_mfma(const bfraw* __restrict__ qq,
                                                const bfraw* __restrict__ kk,
                                                bfraw* __restrict__ attn) {
    int bg = blockIdx.y;
    int tid = blockIdx.x;
    int ry = (tid == 0) ? 0 : 1;
    int rx = (tid == 2) ? 1 : 0;
    int row0 = ry * 128, col0 = rx * 128;
    __shared__ __align__(16) char smem_[16896];
    bfraw* As = (bfraw*)smem_;
    bfraw* Bs = As + 128 * 32;
    float* epi = (float*)smem_;
    int t = threadIdx.x;
    int lane = t & 63, wid = t >> 6;
    int wm = wid >> 1, wn = wid & 1;
    int q = lane >> 4, mi = lane & 15;
    f32x4 acc[4][4] = {};
    const bfraw* Ag = qq + (size_t)(bg * GRP + row0) * QKD;
    const bfraw* Bg = kk + (size_t)(bg * GRP + col0) * QKD;
    for (int k0 = 0; k0 < QKD; k0 += 32) {
        stage128(Ag + k0, QKD, As, t, wid);
        stage128(Bg + k0, QKD, Bs, t, wid);
        __syncthreads();
        mfma_step(As, Bs, acc, wm, wn, q, mi);
        __syncthreads();
    }
    bfraw* ag = attn + (size_t)bg * GRP * GRP;
    #pragma unroll
    for (int p = 0; p < 4; ++p) {
        #pragma unroll
        for (int j = 0; j < 4; ++j) {
            int colg = col0 + wn * 64 + j * 16 + mi;
            #pragma unroll
            for (int rg = 0; rg < 4; ++rg) {
                int rowg = row0 + wm * 64 + p * 16 + q * 4 + rg;
                float s = acc[p][j][rg] * (1.f / GRP);
                s = fmaxf(s, 0.f);
                s = s * s;
                epi[(wm * 16 + q * 4 + rg) * EPIW + wn * 64 + j * 16 + mi] =
                    (colg > rowg) ? 0.f : s;
            }
        }
        __syncthreads();
        int lr = t >> 3, c0t = (t & 7) * 16;
        int gr = row0 + epi_row(p, lr);
        const float* src = &epi[lr * EPIW + c0t];
        u16x8 s0, s1;
        #pragma unroll
        for (int k = 0; k < 8; ++k) s0[k] = f2bf(src[k]);
        #pragma unroll
        for (int k = 0; k < 8; ++k) s1[k] = f2bf(src[8 + k]);
        bfraw* dst = ag + (size_t)gr * GRP + col0 + c0t;
        *(u16x8*)dst = s0;
        *(u16x8*)(dst + 8) = s1;
        __syncthreads();
    }
}

// ------------- kvT_raw[bg][e][d] = sum_j vT[bg][e][j] * lkT[bg][d][j]  (bf16 out) -------------
__global__ __launch_bounds__(256) void kv_mfma(const bfraw* __restrict__ vT,
                                               const bfraw* __restrict__ lkT,
                                               bfraw* __restrict__ kvT_raw) {
    int bg = blockIdx.z;
    int row0 = blockIdx.y * 128;
    __shared__ __align__(16) char smem_[16896];
    bfraw* As = (bfraw*)smem_;
    bfraw* Bs = As + 128 * 32;
    float* epi = (float*)smem_;
    int t = threadIdx.x;
    int lane = t & 63, wid = t >> 6;
    int wm = wid >> 1, wn = wid & 1;
    int q = lane >> 4, mi = lane & 15;
    f32x4 acc[4][4] = {};
    const bfraw* Ag = vT + (size_t)bg * HIDD * GRP + (size_t)row0 * GRP;
    const bfraw* Bg = lkT + (size_t)bg * QKD * GRP;
    for (int k0 = 0; k0 < GRP; k0 += 32) {
        stage128(Ag + k0, GRP, As, t, wid);
        stage128(Bg + k0, GRP, Bs, t, wid);
        __syncthreads();
        mfma_step(As, Bs, acc, wm, wn, q, mi);
        __syncthreads();
    }
    bfraw* outg = kvT_raw + (size_t)bg * HIDD * QKD;
    #pragma unroll
    for (int p = 0; p < 4; ++p) {
        #pragma unroll
        for (int j = 0; j < 4; ++j)
            #pragma unroll
            for (int rg = 0; rg < 4; ++rg)
                epi[(wm * 16 + q * 4 + rg) * EPIW + wn * 64 + j * 16 + mi] = acc[p][j][rg];
        __syncthreads();
        int lr = t >> 3, c0t = (t & 7) * 16;
        int gr = row0 + epi_row(p, lr);
        const float* src = &epi[lr * EPIW + c0t];
        u16x8 s0, s1;
        #pragma unroll
        for (int k = 0; k < 8; ++k) s0[k] = f2bf(src[k]);
        #pragma unroll
        for (int k = 0; k < 8; ++k) s1[k] = f2bf(src[8 + k]);
        bfraw* dst = outg + (size_t)gr * QKD + c0t;
        *(u16x8*)dst = s0;
        *(u16x8*)(dst + 8) = s1;
        __syncthreads();
    }
}

// ------------- exclusive cumsum over groups: kvT_ex[bg][e][d], incl /G scale -------------
__global__ __launch_bounds__(256) void cumsum2_kernel(const bfraw* __restrict__ raw,
                                                      bfraw* __restrict__ ex) {
    int idx = blockIdx.x * 256 + threadIdx.x;   // 0 .. 4*1024*128-1
    int b = idx >> 17;                          // / (1024*128)
    int r = idx & 131071;
    const bfraw* rp = raw + (size_t)b * NGRP * 131072 + r;
    bfraw* ep = ex + (size_t)b * NGRP * 131072 + r;
    float run = 0.f;
    #pragma unroll
    for (int g = 0; g < NGRP; ++g) {
        ep[(size_t)g * 131072] = f2bf(run);
        run += bf2f(rp[(size_t)g * 131072]) * (1.f / GRP);
    }
}

// ------------- gated = gate .* (attn@vv + lq@kv_ex)  (bf16 out) -------------
// grid (8 e-tiles, 2 row-tiles, 64 groups)
__global__ __launch_bounds__(256) void quadlin_mfma(const bfraw* __restrict__ attn,
                                                    const bfraw* __restrict__ vT,
                                                    const bfraw* __restrict__ lq,
                                                    const bfraw* __restrict__ kvT_ex,
                                                    const bfraw* __restrict__ gate,
                                                    bfraw* __restrict__ gated) {
    int bg = blockIdx.z;
    int row0 = blockIdx.y * 128;
    int col0 = blockIdx.x * 128;
    __shared__ __align__(16) char smem_[16896];
    bfraw* As = (bfraw*)smem_;
    bfraw* Bs = As + 128 * 32;
    float* epi = (float*)smem_;
    int t = threadIdx.x;
    int lane = t & 63, wid = t >> 6;
    int wm = wid >> 1, wn = wid & 1;
    int q = lane >> 4, mi = lane & 15;
    f32x4 acc[4][4] = {};
    // Part 1: quadratic. A = attn rows (stride 256), BT = vT rows (stride 256).
    const bfraw* Ag = attn + (size_t)bg * GRP * GRP + (size_t)row0 * GRP;
    const bfraw* Bg = vT + (size_t)bg * HIDD * GRP + (size_t)col0 * GRP;
    int kmax = row0 + 128;     // causal: attn[i][j]=0 for j>i
    for (int k0 = 0; k0 < kmax; k0 += 32) {
        stage128(Ag + k0, GRP, As, t, wid);
        stage128(Bg + k0, GRP, Bs, t, wid);
        __syncthreads();
        mfma_step(As, Bs, acc, wm, wn, q, mi);
        __syncthreads();
    }
    // Part 2: linear. A = lq rows (stride 128), BT = kvT_ex rows (stride 128).
    const bfraw* Ag2 = lq + (size_t)(bg * GRP + row0) * QKD;
    const bfraw* Bg2 = kvT_ex + (size_t)bg * HIDD * QKD + (size_t)col0 * QKD;
    for (int k0 = 0; k0 < QKD; k0 += 32) {
        stage128(Ag2 + k0, QKD, As, t, wid);
        stage128(Bg2 + k0, QKD, Bs, t, wid);
        __syncthreads();
        mfma_step(As, Bs, acc, wm, wn, q, mi);
        __syncthreads();
    }
    #pragma unroll
    for (int p = 0; p < 4; ++p) {
        #pragma unroll
        for (int j = 0; j < 4; ++j)
            #pragma unroll
            for (int rg = 0; rg < 4; ++rg)
                epi[(wm * 16 + q * 4 + rg) * EPIW + wn * 64 + j * 16 + mi] = acc[p][j][rg];
        __syncthreads();
        int lr = t >> 3, c0t = (t & 7) * 16;
        int gr = row0 + epi_row(p, lr);          // group-local row
        size_t grow = (size_t)bg * GRP + gr;
        const float* src = &epi[lr * EPIW + c0t];
        const bfraw* gsrc = gate + grow * HIDD + col0 + c0t;
        u16x8 g0 = *(const u16x8*)gsrc;
        u16x8 g1 = *(const u16x8*)(gsrc + 8);
        u16x8 s0, s1;
        #pragma unroll
        for (int k = 0; k < 8; ++k) s0[k] = f2bf(src[k] * bf2f(g0[k]));
        #pragma unroll
        for (int k = 0; k < 8; ++k) s1[k] = f2bf(src[8 + k] * bf2f(g1[k]));
        bfraw* dst = gated + grow * HIDD + col0 + c0t;
        *(u16x8*)dst = s0;
        *(u16x8*)(dst + 8) = s1;
        __syncthreads();
    }
}

// ------------- final: out = gated @ WoT^T + bo + x  (fp32 out) -------------
__global__ __launch_bounds__(256) void gemm_final(const bfraw* __restrict__ A,
                                                  const bfraw* __restrict__ BT,
                                                  const float* __restrict__ bo,
                                                  const float* __restrict__ x,
                                                  float* __restrict__ out) {
    __shared__ __align__(16) char smem_[16896];
    bfraw* As = (bfraw*)smem_;
    bfraw* Bs = As + 128 * 32;
    float* epi = (float*)smem_;
    int t = threadIdx.x;
    int lane = t & 63, wid = t >> 6;
    int wm = wid >> 1, wn = wid & 1;
    int q = lane >> 4, mi = lane & 15;
    int row0 = blockIdx.y * 128, col0 = blockIdx.x * 128;
    f32x4 acc[4][4] = {};
    for (int k0 = 0; k0 < HIDD; k0 += 32) {
        stage128(A + (size_t)row0 * HIDD + k0, HIDD, As, t, wid);
        stage128(BT + (size_t)col0 * HIDD + k0, HIDD, Bs, t, wid);
        __syncthreads();
        mfma_step(As, Bs, acc, wm, wn, q, mi);
        __syncthreads();
    }
    #pragma unroll
    for (int p = 0; p < 4; ++p) {
        #pragma unroll
        for (int j = 0; j < 4; ++j) {
            float bv = bo[col0 + wn * 64 + j * 16 + mi];
            #pragma unroll
            for (int rg = 0; rg < 4; ++rg)
                epi[(wm * 16 + q * 4 + rg) * EPIW + wn * 64 + j * 16 + mi] =
                    acc[p][j][rg] + bv;
        }
        __syncthreads();
        int lr = t >> 3, c0t = (t & 7) * 16;
        int gr = row0 + epi_row(p, lr);
        const float* src = &epi[lr * EPIW + c0t];
        const float* xsrc = x + (size_t)gr * DIMD + col0 + c0t;
        float* dst = out + (size_t)gr * DIMD + col0 + c0t;
        #pragma unroll
        for (int v = 0; v < 4; ++v) {
            float4 a = ((const float4*)src)[v];
            float4 xv = ((const float4*)xsrc)[v];
            a.x += xv.x; a.y += xv.y; a.z += xv.z; a.w += xv.w;
            ((float4*)dst)[v] = a;
        }
        __syncthreads();
    }
}

extern "C" void kernel_launch(void* const* d_in, const int* in_sizes, int n_in,
                              void* d_out, int out_size, void* d_ws, size_t ws_size,
                              hipStream_t stream) {
    const float* x     = (const float*)d_in[0];
    const float* ln_w  = (const float*)d_in[1];
    const float* ln_b  = (const float*)d_in[2];
    const float* Wh    = (const float*)d_in[3];
    const float* bh    = (const float*)d_in[4];
    const float* Wqk   = (const float*)d_in[5];
    const float* bqk   = (const float*)d_in[6];
    const float* gamma = (const float*)d_in[7];
    const float* beta  = (const float*)d_in[8];
    const float* Wo    = (const float*)d_in[9];
    const float* bo    = (const float*)d_in[10];
    float* out = (float*)d_out;

    // d_out (32 MiB) hosts short-lived buffers; all dead before gemm_final writes out.
    char* outb_ = (char*)d_out;
    bfraw* attn = (bfraw*)(outb_);                    //  8 MiB [64][256][256]
    bfraw* qq   = (bfraw*)(outb_ + 8388608);          //  4 MiB [16384][128]
    bfraw* kk   = (bfraw*)(outb_ + 12582912);         //  4 MiB
    bfraw* lq   = (bfraw*)(outb_ + 16777216);         //  4 MiB
    bfraw* WhT  = (bfraw*)(outb_ + 20971520);         //  2 MiB [2048][512]
    bfraw* WqkT = (bfraw*)(outb_ + 23068672);         //  128 KiB [128][512]
    // (nothing in d_out is read by gemm_final)

    // ws layout (byte offsets), total 149.1 MiB:
    char* wsb = (char*)d_ws;
    bfraw* vT      = (bfraw*)(wsb);                   // 32 MiB [64][1024][256]
    bfraw* gate    = (bfraw*)(wsb + 33554432);        // 32 MiB [16384][1024]
    bfraw* gated   = (bfraw*)(wsb + 67108864);        // 32 MiB [16384][1024]
    bfraw* normb   = (bfraw*)(wsb + 100663296);       // 16 MiB [16384][512]
    bfraw* kvT_raw = (bfraw*)(wsb + 117440512);       // 16 MiB [64][1024][128]
    bfraw* kvT_ex  = (bfraw*)(wsb + 134217728);       // 16 MiB [64][1024][128]
    bfraw* lkT     = (bfraw*)(wsb + 150994944);       //  4 MiB [64][128][256]
    bfraw* WoT     = (bfraw*)(wsb + 155189248);       //  1 MiB [512][1024]
    // end: 156,237,824 bytes

    // 0-2. weight transposes to bf16 [N][K]
    transpose_f32_bf16<<<dim3(2 * HIDD / 32, DIMD / 32), 256, 0, stream>>>(Wh, WhT, DIMD, 2 * HIDD);
    transpose_f32_bf16<<<dim3(DIMD / 32, HIDD / 32), 256, 0, stream>>>(Wo, WoT, HIDD, DIMD);
    transpose_f32_bf16<<<dim3(QKD / 32, DIMD / 32), 256, 0, stream>>>(Wqk, WqkT, DIMD, QKD);
    // 3. LayerNorm -> normb bf16
    ln_kernel<<<TROWS / 4, 256, 0, stream>>>(x, ln_w, ln_b, normb);
    // 4. h GEMM -> vT (v half, transposed) + gate (row-major)
    gemm_h<<<dim3(2 * HIDD / 128, TROWS / 128), 256, 0, stream>>>(normb, WhT, bh, vT, gate);
    // 5. qk heads -> qq/lq/kk row-major + lkT transposed
    qk_mfma<<<dim3(1, TROWS / 128), 256, 0, stream>>>(normb, WqkT, bqk, gamma, beta, qq, lq, kk, lkT);
    // 6. attn = mask(relu(qq @ kk^T / G)^2)
    sim_mfma<<<dim3(3, BGRP), 256, 0, stream>>>(qq, kk, attn);
    // 7. kvT_raw[e][d] = sum_j vT[e][j]*lkT[d][j]
    kv_mfma<<<dim3(1, HIDD / 128, BGRP), 256, 0, stream>>>(vT, lkT, kvT_raw);
    // 8. exclusive cumsum over groups (with /G) -> kvT_ex
    cumsum2_kernel<<<(BATCH * QKD * HIDD) / 256, 256, 0, stream>>>(kvT_raw, kvT_ex);
    // 9. gated = gate .* (attn@vv + lq@kv_ex)
    quadlin_mfma<<<dim3(HIDD / 128, GRP / 128, BGRP), 256, 0, stream>>>(
        attn, vT, lq, kvT_ex, gate, gated);
    // 10. out = gated @ Wo + bo + x
    gemm_final<<<dim3(DIMD / 128, TROWS / 128), 256, 0, stream>>>(gated, WoT, bo, x, out);
}